// Round 5
// baseline (5215.984 us; speedup 1.0000x reference)
//
#include <hip/hip_runtime.h>
#include <hip/hip_bf16.h>
#include <stdint.h>

#define M_DIM 2048
#define N_DIM 25000
#define K_DIM 32000
#define NT_K  500              // K_DIM / 64

typedef __attribute__((ext_vector_type(8))) short short8;
typedef __attribute__((ext_vector_type(4))) float f32x4;

typedef __attribute__((address_space(1))) const void* as1cv;
typedef __attribute__((address_space(3))) void* as3v;
#define GLDS16(g, l) __builtin_amdgcn_global_load_lds((as1cv)(g), (as3v)(l), 16, 0, 0)

// round-to-nearest-even fp32 -> bf16
__device__ inline unsigned short f2bf(float x) {
  union { float f; unsigned u; } c; c.f = x;
  unsigned u = c.u;
  return (unsigned short)((u + 0x7fffu + ((u >> 16) & 1u)) >> 16);
}

__device__ inline short8 pack8(float4 a, float4 b) {
  short8 s;
  s[0] = (short)f2bf(a.x); s[1] = (short)f2bf(a.y);
  s[2] = (short)f2bf(a.z); s[3] = (short)f2bf(a.w);
  s[4] = (short)f2bf(b.x); s[5] = (short)f2bf(b.y);
  s[6] = (short)f2bf(b.z); s[7] = (short)f2bf(b.w);
  return s;
}

// ---------------- convert kernels (fp32 -> bf16 in workspace) ----------------

__global__ __launch_bounds__(256) void conv_a_kernel(const float* __restrict__ in,
                                                     unsigned short* __restrict__ out) {
  const size_t n8 = (size_t)M_DIM * K_DIM / 8;
  const size_t stride = (size_t)gridDim.x * blockDim.x;
  for (size_t i = (size_t)blockIdx.x * blockDim.x + threadIdx.x; i < n8; i += stride) {
    const float4* p = (const float4*)(in + i * 8);
    float4 v0 = p[0], v1 = p[1];
    *(short8*)(out + i * 8) = pack8(v0, v1);
  }
}

// B rows 24576..25087 only (512 rows, zero-padded past 25000) for the rem kernel.
__global__ __launch_bounds__(256) void conv_b_rem_kernel(const float* __restrict__ in,
                                                         unsigned short* __restrict__ out) {
  const size_t n8 = 512 * (size_t)K_DIM / 8;   // 2,048,000
  const size_t stride = (size_t)gridDim.x * blockDim.x;
  const size_t k8 = K_DIM / 8;  // 4000
  for (size_t i = (size_t)blockIdx.x * blockDim.x + threadIdx.x; i < n8; i += stride) {
    const size_t row = i / k8;
    const size_t grow = 24576 + row;
    short8 s = {0, 0, 0, 0, 0, 0, 0, 0};
    if (grow < N_DIM) {
      const float4* p = (const float4*)(in + grow * K_DIM + (i % k8) * 8);
      float4 v0 = p[0], v1 = p[1];
      s = pack8(v0, v1);
    }
    *(short8*)(out + i * 8) = s;
  }
}

// zero the C tail strip (rows 0..2047, cols 24576..24999) for atomic accumulation
__global__ __launch_bounds__(256) void zero_tail_kernel(float* __restrict__ C) {
  const int ntail = 25000 - 24576;  // 424
  const size_t n = (size_t)M_DIM * ntail;
  const size_t stride = (size_t)gridDim.x * blockDim.x;
  for (size_t i = (size_t)blockIdx.x * blockDim.x + threadIdx.x; i < n; i += stride) {
    const size_t r = i / ntail, c = i % ntail;
    C[r * N_DIM + 24576 + c] = 0.f;
  }
}

// ---------------- 256x256 8-phase GEMM; A via bf16 DMA, B fused fp32->bf16 ----------------
// LDS per buffer: A 256x64 bf16 (32 subtiles 16rx32c, 1024 B), then B same image.
// Swizzle within subtile: 16B-chunk c' = c ^ ((row>>1)&3); A applies it via the
// pre-swizzled GLOBAL source (DMA); B applies it via the per-lane fp32 load addr
// before the in-register cvt + linear ds_write (same final LDS image; read path
// identical for A and B).
//
// Per-wave VMEM issue order per steady iteration (tiles t=buf0, t+1=buf1):
//   P1: Lb0(4) Lb1(4) = B(t+2) fp32 loads; D1,D2 = A(t+1)h1 DMA
//   P4: D3,D4 = A(t+2)h0            P5: Lb0(4) Lb1(4) = B(t+3); D5,D6 = A(t+2)h1
//   P8: D7,D8 = A(t+3)h0            carry-in from prev iter: 2 (A(t+1)h0)
// Wait ledger (outstanding -> vmcnt -> drains):
//   P3:  12 -> vmcnt(6) -> carry(2)+Lb0(4)   [write B(t+2)h0]
//   P4a:  6 -> vmcnt(2) -> Lb1(4)            [write B(t+2)h1]  then issue D3,D4
//   P4b:  4 -> vmcnt(2) -> D1,D2             [A(t+1)h1 ready for P5]
//   P7:  12 -> vmcnt(6) -> D3,D4+Lb0(4)      [write B(t+3)h0]
//   P8a:  6 -> vmcnt(2) -> Lb1(4)            [write B(t+3)h1]  then issue D7,D8
//   P8b:  4 -> vmcnt(2) -> D5,D6             [A(t+2)h1 ready for next P1]

#define BARR  __builtin_amdgcn_s_barrier()
#define LGKM0 do { asm volatile("s_waitcnt lgkmcnt(0)" ::: "memory"); \
                   __builtin_amdgcn_sched_barrier(0); } while (0)
#define LGKM8 asm volatile("s_waitcnt lgkmcnt(8)" ::: "memory")
#define VMC14 asm volatile("s_waitcnt vmcnt(14)" ::: "memory")
#define VMC6  asm volatile("s_waitcnt vmcnt(6)" ::: "memory")
#define VMC2  asm volatile("s_waitcnt vmcnt(2)" ::: "memory")
#define VMC0  asm volatile("s_waitcnt vmcnt(0)" ::: "memory")
#define PRIO1 __builtin_amdgcn_s_setprio(1)
#define PRIO0 __builtin_amdgcn_s_setprio(0)

#define READ_AF(P, MH) { _Pragma("unroll") for (int m2_ = 0; m2_ < 4; ++m2_) { \
  _Pragma("unroll") for (int kk_ = 0; kk_ < 2; ++kk_) \
    af[m2_][kk_] = *(const short8*)(rdA##P + (((MH) * 4 + m2_) * 2 + kk_) * 512); } }

#define READ_BF(P, NH) { _Pragma("unroll") for (int n2_ = 0; n2_ < 2; ++n2_) { \
  _Pragma("unroll") for (int kk_ = 0; kk_ < 2; ++kk_) \
    bf[NH][n2_][kk_] = *(const short8*)(rdB##P + (((NH) * 2 + n2_) * 2 + kk_) * 512); } }

#define MFMA_Q(MH, NH) { _Pragma("unroll") for (int kk_ = 0; kk_ < 2; ++kk_) { \
  _Pragma("unroll") for (int m2_ = 0; m2_ < 4; ++m2_) { \
  _Pragma("unroll") for (int n2_ = 0; n2_ < 2; ++n2_) \
    acc[(MH)*4+m2_][(NH)*2+n2_] = __builtin_amdgcn_mfma_f32_16x16x32_bf16( \
        af[m2_][kk_], bf[NH][n2_][kk_], acc[(MH)*4+m2_][(NH)*2+n2_], 0, 0, 0); } } }

#define STAGE_A(P, KT, H) do { \
  const unsigned short* s_ = agp + (size_t)(H) * (128 * (size_t)K_DIM) + (size_t)(KT) * 64; \
  GLDS16(s_,      stA##P + (H) * 8192); \
  GLDS16(s_ + 32, stA##P + (H) * 8192 + 512); } while (0)

// B fp32 loads: lane covers row srow of half H, swizzled-source chunk (8 f32)
// in each of the two 32-col subtiles (kk=0,1). 4x dwordx4 per half.
#define LOAD_B(R, KT, H) do { \
  const float* p_ = bq + (size_t)(H) * (128 * (size_t)K_DIM) + (size_t)(KT) * 64; \
  R[0] = *(const float4*)(p_);      R[1] = *(const float4*)(p_ + 4); \
  R[2] = *(const float4*)(p_ + 32); R[3] = *(const float4*)(p_ + 36); } while (0)

// cvt + linear ds_write reproducing the DMA's LDS image (lane slot = row l>>2, chunk l&3)
#define WRITE_B(P, H, R) do { \
  unsigned short* wp_ = stB##P + (H) * 8192 + wboff; \
  *(short8*)(wp_)       = pack8(R[0], R[1]); \
  *(short8*)(wp_ + 512) = pack8(R[2], R[3]); } while (0)

__global__ __launch_bounds__(512, 2)
void gemm8_kernel(const unsigned short* __restrict__ A, const float* __restrict__ Bf,
                  float* __restrict__ C) {
  extern __shared__ __align__(16) unsigned short lds[];  // 131072 B
  unsigned short* const LA0 = lds;
  unsigned short* const LB0 = lds + 16384;
  unsigned short* const LA1 = lds + 32768;
  unsigned short* const LB1 = lds + 49152;

  const int bid = blockIdx.x;
  const int wg = (bid & 7) * 96 + (bid >> 3);   // bijective XCD chunking (768 % 8 == 0)
  const int tm = wg & 7;                        // M tile 0..7 (fastest: shares B panel)
  const int tn = wg >> 3;                       // N tile 0..95 (cols 0..24575, all < 25000)
  const int tid = threadIdx.x;
  const int lane = tid & 63;
  const int w = tid >> 6;        // wave 0..7
  const int wm = w >> 2;         // 2 waves in M (128 rows each)
  const int wn = w & 3;          // 4 waves in N (64 cols each)

  const int laneoff = (lane & 15) * 32 + (((lane >> 4) ^ ((lane >> 1) & 3)) << 3);
  const unsigned short* const rdA0 = LA0 + wm * (16 * 512) + laneoff;
  const unsigned short* const rdA1 = LA1 + wm * (16 * 512) + laneoff;
  const int bsub = (wn >> 1) * 16 + (wn & 1) * 8;
  const unsigned short* const rdB0 = LB0 + bsub * 512 + laneoff;
  const unsigned short* const rdB1 = LB1 + bsub * 512 + laneoff;

  const int srow = w * 16 + (lane >> 2);
  const int schunk = ((lane & 3) ^ ((lane >> 3) & 3)) * 8;   // element offset (bf16 or f32)
  const unsigned short* const agp = A + (size_t)(tm * 256 + srow) * K_DIM + schunk;
  const float* const bq = Bf + (size_t)(tn * 256 + srow) * K_DIM + schunk;
  unsigned short* const stA0 = LA0 + w * 1024;
  unsigned short* const stA1 = LA1 + w * 1024;
  unsigned short* const stB0 = LB0 + w * 1024;
  unsigned short* const stB1 = LB1 + w * 1024;
  const int wboff = (lane >> 2) * 32 + (lane & 3) * 8;       // ushort offset within subtile-pair

  f32x4 acc[8][4];
  const f32x4 z4 = {0.f, 0.f, 0.f, 0.f};
  #pragma unroll
  for (int i = 0; i < 8; ++i)
    #pragma unroll
    for (int j = 0; j < 4; ++j) acc[i][j] = z4;

  short8 af[4][2];      // current mh: 4 m-frags x 2 k-slices
  short8 bf[2][2][2];   // [nh][n'][kk]
  float4 lb0[4], lb1[4];

  // ---- prologue: B(0),B(1) via reg path; A(0)h0,h1 + A(1)h0 via DMA ----
  {
    float4 lc0[4], lc1[4];
    LOAD_B(lb0, 0, 0); LOAD_B(lb1, 0, 1);     // B(0): 8 loads
    LOAD_B(lc0, 1, 0); LOAD_B(lc1, 1, 1);     // B(1): 8 loads
    STAGE_A(0, 0, 0); STAGE_A(0, 0, 1);       // A(0): 4 DMA
    STAGE_A(1, 1, 0);                          // A(1)h0: 2 DMA
    VMC14;                                     // B(0) done (leaves B(1)8 + A6)
    WRITE_B(0, 0, lb0); WRITE_B(0, 1, lb1);
    VMC6;                                      // B(1) done (leaves A6)
    WRITE_B(1, 0, lc0); WRITE_B(1, 1, lc1);
    VMC2;                                      // A(0) done (leaves A(1)h0 = carry-in 2)
    LGKM0;                                     // ds_writes done
    BARR;
  }

  // ---- main loop: tiles (t, t+1), t = 0,2,...,496 ----
  #pragma unroll 1
  for (int it = 0; it < 249; ++it) {
    const int t = 2 * it;
    // P1: reads Q(0,0); issue B(t+2) fp32 loads; stage A(t+1)h1 -> buf1
    READ_AF(0, 0); READ_BF(0, 0);
    LOAD_B(lb0, t + 2, 0); LOAD_B(lb1, t + 2, 1);
    STAGE_A(1, t + 1, 1);
    LGKM8; BARR; LGKM0; PRIO1; MFMA_Q(0, 0); PRIO0; BARR;
    // P2
    READ_BF(0, 1);
    BARR; LGKM0; PRIO1; MFMA_Q(0, 1); PRIO0; BARR;
    // P3: write B(t+2)h0 -> buf0  [buf0.Bh0 free after P1]
    READ_AF(0, 1);
    VMC6; WRITE_B(0, 0, lb0);
    BARR; LGKM0; PRIO1; MFMA_Q(1, 1); PRIO0; BARR;
    // P4: write B(t+2)h1 -> buf0 [free after P2]; stage A(t+2)h0; wait A(t+1)h1
    VMC2; WRITE_B(0, 1, lb1);
    STAGE_A(0, t + 2, 0);
    BARR; PRIO1; MFMA_Q(1, 0); PRIO0; VMC2; BARR;
    // P5: reads Q(0,0) of t+1; issue B(t+3) loads; stage A(t+2)h1
    READ_AF(1, 0); READ_BF(1, 0);
    LOAD_B(lb0, t + 3, 0); LOAD_B(lb1, t + 3, 1);
    STAGE_A(0, t + 2, 1);
    LGKM8; BARR; LGKM0; PRIO1; MFMA_Q(0, 0); PRIO0; BARR;
    // P6
    READ_BF(1, 1);
    BARR; LGKM0; PRIO1; MFMA_Q(0, 1); PRIO0; BARR;
    // P7: write B(t+3)h0 -> buf1  [free after P6... h0 free after P5]
    READ_AF(1, 1);
    VMC6; WRITE_B(1, 0, lb0);
    BARR; LGKM0; PRIO1; MFMA_Q(1, 1); PRIO0; BARR;
    // P8: write B(t+3)h1 -> buf1; stage A(t+3)h0; wait A(t+2)h1
    VMC2; WRITE_B(1, 1, lb1);
    STAGE_A(1, t + 3, 0);
    BARR; PRIO1; MFMA_Q(1, 0); PRIO0; VMC2; BARR;
  }

  // ---- tail: tile 498 (buf0; stage A(499)h1 only), then tile 499 (buf1) ----
  READ_AF(0, 0); READ_BF(0, 0); STAGE_A(1, 499, 1);
  LGKM8; BARR; LGKM0; PRIO1; MFMA_Q(0, 0); PRIO0; BARR;
  READ_BF(0, 1);
  BARR; LGKM0; PRIO1; MFMA_Q(0, 1); PRIO0; BARR;
  READ_AF(0, 1);
  BARR; LGKM0; PRIO1; MFMA_Q(1, 1); PRIO0; BARR;
  BARR; PRIO1; MFMA_Q(1, 0); PRIO0; VMC0; BARR;   // drain A(499)h0 (carry) + h1
  READ_AF(1, 0); READ_BF(1, 0);
  LGKM8; BARR; LGKM0; PRIO1; MFMA_Q(0, 0); PRIO0; BARR;
  READ_BF(1, 1);
  BARR; LGKM0; PRIO1; MFMA_Q(0, 1); PRIO0; BARR;
  READ_AF(1, 1);
  BARR; LGKM0; PRIO1; MFMA_Q(1, 1); PRIO0; BARR;
  PRIO1; MFMA_Q(1, 0); PRIO0;

  // ---- epilogue: C/D layout col=lane&15, row=(lane>>4)*4+j [m89-verified] ----
  const int crow0 = tm * 256 + wm * 128 + (lane >> 4) * 4;
  const int ccol0 = tn * 256 + wn * 64 + (lane & 15);
  #pragma unroll
  for (int m = 0; m < 8; ++m) {
    #pragma unroll
    for (int n = 0; n < 4; ++n) {
      const int col = ccol0 + n * 16;
      float* cp = C + (size_t)(crow0 + m * 16) * N_DIM + col;
      #pragma unroll
      for (int j = 0; j < 4; ++j)
        cp[(size_t)j * N_DIM] = acc[m][n][j];
    }
  }
}

// ---------------- K-split tail: cols 24576..24999, 64 tiles x 8 K-chunks ----------------

__device__ inline void mfma_tile_fb(const unsigned short* As, const unsigned short* Bs,
                                    f32x4 acc[4][4], int lane, int wr, int wc) {
  const int ar = lane & 15;
  const int ko = (lane >> 4) * 8;
  #pragma unroll
  for (int kk = 0; kk < 2; ++kk) {
    short8 a2[4], b2[4];
    #pragma unroll
    for (int m = 0; m < 4; ++m)
      a2[m] = *(const short8*)&As[(wr * 64 + m * 16 + ar) * 64 + kk * 32 + ko];
    #pragma unroll
    for (int n = 0; n < 4; ++n)
      b2[n] = *(const short8*)&Bs[(wc * 64 + n * 16 + ar) * 64 + kk * 32 + ko];
    #pragma unroll
    for (int m = 0; m < 4; ++m)
      #pragma unroll
      for (int n = 0; n < 4; ++n)
        acc[m][n] = __builtin_amdgcn_mfma_f32_16x16x32_bf16(a2[m], b2[n], acc[m][n], 0, 0, 0);
  }
}

__global__ __launch_bounds__(256, 2)
void gemm_rem_split_kernel(const unsigned short* __restrict__ A,
                           const unsigned short* __restrict__ Brem,  // rows 24576..25087
                           float* __restrict__ C) {
  __shared__ __align__(16) unsigned short As[128 * 64];
  __shared__ __align__(16) unsigned short Bs[128 * 64];
  const int bid = blockIdx.x;          // 512 blocks
  const int kc = bid & 7;              // K chunk 0..7
  const int tile = bid >> 3;           // 0..63
  const int tm = tile & 15;            // 16 M tiles of 128
  const int tnr = tile >> 4;           // 0..3 -> Brem rows tnr*128
  const int nsteps = (kc < 4) ? 63 : 62;
  const int kt0 = (kc < 4) ? kc * 63 : 252 + (kc - 4) * 62;
  const int tid = threadIdx.x;
  const int lane = tid & 63;
  const int w = tid >> 6;
  const int wr = w >> 1;
  const int wc = w & 1;
  f32x4 acc[4][4];
  const f32x4 z4 = {0.f, 0.f, 0.f, 0.f};
  #pragma unroll
  for (int i = 0; i < 4; ++i)
    #pragma unroll
    for (int j = 0; j < 4; ++j) acc[i][j] = z4;
  const int lrow = lane >> 3;
  const int lc16 = lane & 7;
  const unsigned short* ag = A + (size_t)(tm * 128 + w * 32 + lrow) * K_DIM + (size_t)kt0 * 64 + lc16 * 8;
  const unsigned short* bg = Brem + (size_t)(tnr * 128 + w * 32 + lrow) * K_DIM + (size_t)kt0 * 64 + lc16 * 8;
  for (int kt = 0; kt < nsteps; ++kt) {
    #pragma unroll
    for (int i = 0; i < 4; ++i) {
      GLDS16(ag + (size_t)(i * 8) * K_DIM, &As[(w * 32 + i * 8) * 64]);
      GLDS16(bg + (size_t)(i * 8) * K_DIM, &Bs[(w * 32 + i * 8) * 64]);
    }
    ag += 64; bg += 64;
    __syncthreads();
    mfma_tile_fb(As, Bs, acc, lane, wr, wc);
    __syncthreads();
  }
  const int crow0 = tm * 128 + wr * 64 + (lane >> 4) * 4;
  const int ccol0 = 24576 + tnr * 128 + wc * 64 + (lane & 15);
  #pragma unroll
  for (int m = 0; m < 4; ++m) {
    #pragma unroll
    for (int n = 0; n < 4; ++n) {
      const int col = ccol0 + n * 16;
      if (col < N_DIM) {
        float* cp = C + (size_t)(crow0 + m * 16) * N_DIM + col;
        #pragma unroll
        for (int j = 0; j < 4; ++j)
          unsafeAtomicAdd(cp + (size_t)j * N_DIM, acc[m][n][j]);
      }
    }
  }
}

// ---------------- fallback (r1-validated 128^2 reg-staged fp32 path) ----------------

__global__ __launch_bounds__(256, 2)
void gemm_fb_kernel(const float* __restrict__ A, const float* __restrict__ B,
                    float* __restrict__ C) {
  __shared__ __align__(16) unsigned short As[128 * 64];
  __shared__ __align__(16) unsigned short Bs[128 * 64];
  const int bid = blockIdx.x;
  const int wg = (bid & 7) * (3136 / 8) + (bid >> 3);
  const int tm = wg % 16;
  const int tn = wg / 16;
  const int tid = threadIdx.x;
  const int lane = tid & 63;
  const int w = tid >> 6;
  const int wr = w >> 1;
  const int wc = w & 1;
  f32x4 acc[4][4];
  const f32x4 z4 = {0.f, 0.f, 0.f, 0.f};
  #pragma unroll
  for (int i = 0; i < 4; ++i)
    #pragma unroll
    for (int j = 0; j < 4; ++j) acc[i][j] = z4;
  for (int kt = 0; kt < NT_K; ++kt) {
    const int k0 = kt * 64;
    #pragma unroll
    for (int r = 0; r < 4; ++r) {
      const int f0 = r * 512 + tid * 2;
      const int row = f0 >> 4;
      const int c4 = f0 & 15;
      const float* ga = A + (size_t)(tm * 128 + row) * K_DIM + k0 + c4 * 4;
      float4 v0 = *(const float4*)ga;
      float4 v1 = *(const float4*)(ga + 4);
      *(short8*)&As[row * 64 + c4 * 4] = pack8(v0, v1);
    }
    #pragma unroll
    for (int r = 0; r < 4; ++r) {
      const int f0 = r * 512 + tid * 2;
      const int row = f0 >> 4;
      const int c4 = f0 & 15;
      const int grow = tn * 128 + row;
      short8 s = {0, 0, 0, 0, 0, 0, 0, 0};
      if (grow < N_DIM) {
        const float* gb = B + (size_t)grow * K_DIM + k0 + c4 * 4;
        float4 v0 = *(const float4*)gb;
        float4 v1 = *(const float4*)(gb + 4);
        s = pack8(v0, v1);
      }
      *(short8*)&Bs[row * 64 + c4 * 4] = s;
    }
    __syncthreads();
    mfma_tile_fb(As, Bs, acc, lane, wr, wc);
    __syncthreads();
  }
  const int crow0 = tm * 128 + wr * 64 + (lane >> 4) * 4;
  const int ccol0 = tn * 128 + wc * 64 + (lane & 15);
  #pragma unroll
  for (int m = 0; m < 4; ++m) {
    #pragma unroll
    for (int n = 0; n < 4; ++n) {
      const int col = ccol0 + n * 16;
      if (col < N_DIM) {
        float* cp = C + (size_t)(crow0 + m * 16) * N_DIM + col;
        #pragma unroll
        for (int j = 0; j < 4; ++j)
          cp[(size_t)j * N_DIM] = acc[m][n][j];
      }
    }
  }
}

// ---------------- launch ----------------

extern "C" void kernel_launch(void* const* d_in, const int* in_sizes, int n_in,
                              void* d_out, int out_size, void* d_ws, size_t ws_size,
                              hipStream_t stream) {
  const float* A = (const float*)d_in[0];   // teacher_logits [2048][32000] fp32
  const float* B = (const float*)d_in[1];   // projection   [25000][32000] fp32
  float* C = (float*)d_out;                 // [2048][25000] fp32

  const size_t needA    = (size_t)M_DIM * K_DIM * 2;   // 131 MB
  const size_t needBrem = (size_t)512 * K_DIM * 2;     // 32.8 MB

  if (ws_size >= needA + needBrem) {
    unsigned short* wsA    = (unsigned short*)d_ws;
    unsigned short* wsBrem = wsA + (size_t)M_DIM * K_DIM;
    conv_a_kernel<<<2048, 256, 0, stream>>>(A, wsA);
    conv_b_rem_kernel<<<1024, 256, 0, stream>>>(B, wsBrem);
    zero_tail_kernel<<<512, 256, 0, stream>>>(C);
    (void)hipFuncSetAttribute((const void*)gemm8_kernel,
                              hipFuncAttributeMaxDynamicSharedMemorySize, 131072);
    gemm8_kernel<<<768, 512, 131072, stream>>>(wsA, B, C);            // cols 0..24575
    gemm_rem_split_kernel<<<512, 256, 0, stream>>>(wsA, wsBrem, C);   // cols 24576..24999
  } else {
    gemm_fb_kernel<<<3136, 256, 0, stream>>>(A, B, C);
  }
}

// Round 6
// 5168.007 us; speedup vs baseline: 1.0093x; 1.0093x over previous
//
#include <hip/hip_runtime.h>
#include <hip/hip_bf16.h>
#include <stdint.h>

#define M_DIM 2048
#define N_DIM 25000
#define K_DIM 32000
#define NT_K  500              // K_DIM / 64

typedef __attribute__((ext_vector_type(8))) short short8;
typedef __attribute__((ext_vector_type(4))) float f32x4;

typedef __attribute__((address_space(1))) const void* as1cv;
typedef __attribute__((address_space(3))) void* as3v;
#define GLDS16(g, l) __builtin_amdgcn_global_load_lds((as1cv)(g), (as3v)(l), 16, 0, 0)

// round-to-nearest-even fp32 -> bf16
__device__ inline unsigned short f2bf(float x) {
  union { float f; unsigned u; } c; c.f = x;
  unsigned u = c.u;
  return (unsigned short)((u + 0x7fffu + ((u >> 16) & 1u)) >> 16);
}

__device__ inline short8 pack8(float4 a, float4 b) {
  short8 s;
  s[0] = (short)f2bf(a.x); s[1] = (short)f2bf(a.y);
  s[2] = (short)f2bf(a.z); s[3] = (short)f2bf(a.w);
  s[4] = (short)f2bf(b.x); s[5] = (short)f2bf(b.y);
  s[6] = (short)f2bf(b.z); s[7] = (short)f2bf(b.w);
  return s;
}

// ---------------- convert kernels (fp32 -> bf16 in workspace) ----------------

__global__ __launch_bounds__(256) void conv_a_kernel(const float* __restrict__ in,
                                                     unsigned short* __restrict__ out) {
  const size_t n8 = (size_t)M_DIM * K_DIM / 8;
  const size_t stride = (size_t)gridDim.x * blockDim.x;
  for (size_t i = (size_t)blockIdx.x * blockDim.x + threadIdx.x; i < n8; i += stride) {
    const float4* p = (const float4*)(in + i * 8);
    float4 v0 = p[0], v1 = p[1];
    *(short8*)(out + i * 8) = pack8(v0, v1);
  }
}

// B rows 24576..25087 only (512 rows, zero-padded past 25000) for the rem kernel.
__global__ __launch_bounds__(256) void conv_b_rem_kernel(const float* __restrict__ in,
                                                         unsigned short* __restrict__ out) {
  const size_t n8 = 512 * (size_t)K_DIM / 8;   // 2,048,000
  const size_t stride = (size_t)gridDim.x * blockDim.x;
  const size_t k8 = K_DIM / 8;  // 4000
  for (size_t i = (size_t)blockIdx.x * blockDim.x + threadIdx.x; i < n8; i += stride) {
    const size_t row = i / k8;
    const size_t grow = 24576 + row;
    short8 s = {0, 0, 0, 0, 0, 0, 0, 0};
    if (grow < N_DIM) {
      const float4* p = (const float4*)(in + grow * K_DIM + (i % k8) * 8);
      float4 v0 = p[0], v1 = p[1];
      s = pack8(v0, v1);
    }
    *(short8*)(out + i * 8) = s;
  }
}

// zero the C tail strip (rows 0..2047, cols 24576..24999) for atomic accumulation
__global__ __launch_bounds__(256) void zero_tail_kernel(float* __restrict__ C) {
  const int ntail = 25000 - 24576;  // 424
  const size_t n = (size_t)M_DIM * ntail;
  const size_t stride = (size_t)gridDim.x * blockDim.x;
  for (size_t i = (size_t)blockIdx.x * blockDim.x + threadIdx.x; i < n; i += stride) {
    const size_t r = i / ntail, c = i % ntail;
    C[r * N_DIM + 24576 + c] = 0.f;
  }
}

// ---------------- 256x256 8-phase GEMM; A via bf16 DMA, B fused fp32->bf16 ----------------
// B-fusion with 6-PHASE prefetch depth (r5 failed at 2-phase depth -> latency stall):
//   two live B register sets; loads issued 6 phases before their LDS write.
// Per-wave VMEM issue order, steady iteration (tiles t=buf0, t+1=buf1):
//   P1: DMA A(t+1)h1 (2) then lbY <- B(t+3) (8)
//   P4: DMA A(t+2)h0 (2)
//   P5: DMA A(t+2)h1 (2) then lbX <- B(t+4) (8)
//   P8: DMA A(t+3)h0 (2)
// FIFO ledger (enter P1: [lbX8, A(t+1)h0_2] = 10):
//   P3:  20 -> vmcnt(12): drains lbX (oldest 8)  -> write buf0.B h0 (h1 at P4)
//   eP4: 14 -> vmcnt(10): drains A(t+1) (oldest 4)
//   P7:  20 -> vmcnt(12): drains lbY             -> write buf1.B h0 (h1 at P8)
//   eP8: 14 -> vmcnt(10): drains A(t+2) -> leaves [lbX8, A(t+3)h0_2] = enter state
// A-DMAs issued before same-phase B loads so tile waits never force B drains;
// prefix-drain invariant: waited ops are always the oldest entries.

#define BARR  __builtin_amdgcn_s_barrier()
#define LGKM0 do { asm volatile("s_waitcnt lgkmcnt(0)" ::: "memory"); \
                   __builtin_amdgcn_sched_barrier(0); } while (0)
#define LGKM8 asm volatile("s_waitcnt lgkmcnt(8)" ::: "memory")
#define VMC12 asm volatile("s_waitcnt vmcnt(12)" ::: "memory")
#define VMC10 asm volatile("s_waitcnt vmcnt(10)" ::: "memory")
#define VMC0  asm volatile("s_waitcnt vmcnt(0)" ::: "memory")
#define PRIO1 __builtin_amdgcn_s_setprio(1)
#define PRIO0 __builtin_amdgcn_s_setprio(0)

#define READ_AF(P, MH) { _Pragma("unroll") for (int m2_ = 0; m2_ < 4; ++m2_) { \
  _Pragma("unroll") for (int kk_ = 0; kk_ < 2; ++kk_) \
    af[m2_][kk_] = *(const short8*)(rdA##P + (((MH) * 4 + m2_) * 2 + kk_) * 512); } }

#define READ_BF(P, NH) { _Pragma("unroll") for (int n2_ = 0; n2_ < 2; ++n2_) { \
  _Pragma("unroll") for (int kk_ = 0; kk_ < 2; ++kk_) \
    bf[NH][n2_][kk_] = *(const short8*)(rdB##P + (((NH) * 2 + n2_) * 2 + kk_) * 512); } }

#define MFMA_Q(MH, NH) { _Pragma("unroll") for (int kk_ = 0; kk_ < 2; ++kk_) { \
  _Pragma("unroll") for (int m2_ = 0; m2_ < 4; ++m2_) { \
  _Pragma("unroll") for (int n2_ = 0; n2_ < 2; ++n2_) \
    acc[(MH)*4+m2_][(NH)*2+n2_] = __builtin_amdgcn_mfma_f32_16x16x32_bf16( \
        af[m2_][kk_], bf[NH][n2_][kk_], acc[(MH)*4+m2_][(NH)*2+n2_], 0, 0, 0); } } }

#define STAGE_A(P, KT, H) do { \
  const unsigned short* s_ = agp + (size_t)(H) * (128 * (size_t)K_DIM) + (size_t)(KT) * 64; \
  GLDS16(s_,      stA##P + (H) * 8192); \
  GLDS16(s_ + 32, stA##P + (H) * 8192 + 512); } while (0)

// B fp32 loads for one 128-row half: lane's swizzled 8-float chunk in each of
// the two 32-col subtiles (4x dwordx4). R = float4[4].
#define LOAD_B(R, KT, H) do { \
  const float* p_ = bq + (size_t)(H) * (128 * (size_t)K_DIM) + (size_t)(KT) * 64; \
  (R)[0] = *(const float4*)(p_);      (R)[1] = *(const float4*)(p_ + 4); \
  (R)[2] = *(const float4*)(p_ + 32); (R)[3] = *(const float4*)(p_ + 36); } while (0)

// cvt + linear ds_write reproducing the DMA's LDS image
#define WRITE_B(P, H, R) do { \
  unsigned short* wp_ = stB##P + (H) * 8192 + wboff; \
  *(short8*)(wp_)       = pack8((R)[0], (R)[1]); \
  *(short8*)(wp_ + 512) = pack8((R)[2], (R)[3]); } while (0)

__global__ __launch_bounds__(512, 2)
void gemm8_kernel(const unsigned short* __restrict__ A, const float* __restrict__ Bf,
                  float* __restrict__ C) {
  extern __shared__ __align__(16) unsigned short lds[];  // 131072 B
  unsigned short* const LA0 = lds;
  unsigned short* const LB0 = lds + 16384;
  unsigned short* const LA1 = lds + 32768;
  unsigned short* const LB1 = lds + 49152;

  const int bid = blockIdx.x;
  const int wg = (bid & 7) * 96 + (bid >> 3);   // bijective XCD chunking (768 % 8 == 0)
  const int tm = wg & 7;                        // M tile 0..7 (fastest: shares B panel)
  const int tn = wg >> 3;                       // N tile 0..95 (cols 0..24575)
  const int tid = threadIdx.x;
  const int lane = tid & 63;
  const int w = tid >> 6;        // wave 0..7
  const int wm = w >> 2;         // 2 waves in M (128 rows each)
  const int wn = w & 3;          // 4 waves in N (64 cols each)

  const int laneoff = (lane & 15) * 32 + (((lane >> 4) ^ ((lane >> 1) & 3)) << 3);
  const unsigned short* const rdA0 = LA0 + wm * (16 * 512) + laneoff;
  const unsigned short* const rdA1 = LA1 + wm * (16 * 512) + laneoff;
  const int bsub = (wn >> 1) * 16 + (wn & 1) * 8;
  const unsigned short* const rdB0 = LB0 + bsub * 512 + laneoff;
  const unsigned short* const rdB1 = LB1 + bsub * 512 + laneoff;

  const int srow = w * 16 + (lane >> 2);
  const int schunk = ((lane & 3) ^ ((lane >> 3) & 3)) * 8;   // element offset
  const unsigned short* const agp = A + (size_t)(tm * 256 + srow) * K_DIM + schunk;
  const float* const bq = Bf + (size_t)(tn * 256 + srow) * K_DIM + schunk;
  unsigned short* const stA0 = LA0 + w * 1024;
  unsigned short* const stA1 = LA1 + w * 1024;
  unsigned short* const stB0 = LB0 + w * 1024;
  unsigned short* const stB1 = LB1 + w * 1024;
  const int wboff = (lane >> 2) * 32 + (lane & 3) * 8;

  f32x4 acc[8][4];
  const f32x4 z4 = {0.f, 0.f, 0.f, 0.f};
  #pragma unroll
  for (int i = 0; i < 8; ++i)
    #pragma unroll
    for (int j = 0; j < 4; ++j) acc[i][j] = z4;

  short8 af[4][2];      // current mh: 4 m-frags x 2 k-slices
  short8 bf[2][2][2];   // [nh][n'][kk]
  float4 lbx[8], lby[8];  // two B register sets (h0 = [0..3], h1 = [4..7])

  // ---- prologue: B(0),B(1) loaded+written; A(0) DMA; then preload steady state ----
  LOAD_B(lby, 0, 0);   LOAD_B(lby + 4, 0, 1);   // B(0)
  STAGE_A(0, 0, 0); STAGE_A(0, 0, 1);           // A(0): 4 DMA
  LOAD_B(lbx, 1, 0);   LOAD_B(lbx + 4, 1, 1);   // B(1)
  VMC0;                                          // one-time full drain
  WRITE_B(0, 0, lby); WRITE_B(0, 1, lby + 4);   // buf0.B = B(0)
  WRITE_B(1, 0, lbx); WRITE_B(1, 1, lbx + 4);   // buf1.B = B(1)
  LOAD_B(lbx, 2, 0);   LOAD_B(lbx + 4, 2, 1);   // lbX = B(2)   (oldest in queue)
  STAGE_A(1, 1, 0);                              // A(1)h0 -> Q = [lbX8, A1h0_2]
  LGKM0; BARR;

  // ---- main loop: tiles (t, t+1), t = 0,2,...,496 ----
  #pragma unroll 1
  for (int it = 0; it < 249; ++it) {
    const int t = 2 * it;
    // P1: reads Q(0,0); DMA A(t+1)h1; issue lbY <- B(t+3)
    READ_AF(0, 0); READ_BF(0, 0);
    STAGE_A(1, t + 1, 1);
    LOAD_B(lby, t + 3, 0); LOAD_B(lby + 4, t + 3, 1);
    LGKM8; BARR; LGKM0; PRIO1; MFMA_Q(0, 0); PRIO0; BARR;
    // P2
    READ_BF(0, 1);
    BARR; LGKM0; PRIO1; MFMA_Q(0, 1); PRIO0; BARR;
    // P3: lbX done (6-phase depth) -> write buf0.Bh0
    READ_AF(0, 1);
    VMC12; WRITE_B(0, 0, lbx);
    BARR; LGKM0; PRIO1; MFMA_Q(1, 1); PRIO0; BARR;
    // P4: write buf0.Bh1; DMA A(t+2)h0; wait A(t+1) complete
    WRITE_B(0, 1, lbx + 4);
    STAGE_A(0, t + 2, 0);
    BARR; PRIO1; MFMA_Q(1, 0); PRIO0; VMC10; BARR;
    // P5: reads for t+1; DMA A(t+2)h1; issue lbX <- B(t+4)
    READ_AF(1, 0); READ_BF(1, 0);
    STAGE_A(0, t + 2, 1);
    LOAD_B(lbx, t + 4, 0); LOAD_B(lbx + 4, t + 4, 1);
    LGKM8; BARR; LGKM0; PRIO1; MFMA_Q(0, 0); PRIO0; BARR;
    // P6
    READ_BF(1, 1);
    BARR; LGKM0; PRIO1; MFMA_Q(0, 1); PRIO0; BARR;
    // P7: lbY done (6-phase depth) -> write buf1.Bh0
    READ_AF(1, 1);
    VMC12; WRITE_B(1, 0, lby);
    BARR; LGKM0; PRIO1; MFMA_Q(1, 1); PRIO0; BARR;
    // P8: write buf1.Bh1; DMA A(t+3)h0; wait A(t+2) complete
    WRITE_B(1, 1, lby + 4);
    STAGE_A(1, t + 3, 0);
    BARR; PRIO1; MFMA_Q(1, 0); PRIO0; VMC10; BARR;
  }
  // note: last iteration's lbX <- B(500) reads in-bounds garbage (next row's
  // floats), never written; drained by the tail's VMC0.

  // ---- tail: tile 498 (buf0; DMA A(499)h1), then tile 499 (buf1) ----
  READ_AF(0, 0); READ_BF(0, 0); STAGE_A(1, 499, 1);
  LGKM8; BARR; LGKM0; PRIO1; MFMA_Q(0, 0); PRIO0; BARR;
  READ_BF(0, 1);
  BARR; LGKM0; PRIO1; MFMA_Q(0, 1); PRIO0; BARR;
  READ_AF(0, 1);
  BARR; LGKM0; PRIO1; MFMA_Q(1, 1); PRIO0; BARR;
  BARR; PRIO1; MFMA_Q(1, 0); PRIO0; VMC0; BARR;   // drain garbage lbX + A(499)
  READ_AF(1, 0); READ_BF(1, 0);
  LGKM8; BARR; LGKM0; PRIO1; MFMA_Q(0, 0); PRIO0; BARR;
  READ_BF(1, 1);
  BARR; LGKM0; PRIO1; MFMA_Q(0, 1); PRIO0; BARR;
  READ_AF(1, 1);
  BARR; LGKM0; PRIO1; MFMA_Q(1, 1); PRIO0; BARR;
  PRIO1; MFMA_Q(1, 0); PRIO0;

  // ---- epilogue: C/D layout col=lane&15, row=(lane>>4)*4+j [m89-verified] ----
  const int crow0 = tm * 256 + wm * 128 + (lane >> 4) * 4;
  const int ccol0 = tn * 256 + wn * 64 + (lane & 15);
  #pragma unroll
  for (int m = 0; m < 8; ++m) {
    #pragma unroll
    for (int n = 0; n < 4; ++n) {
      const int col = ccol0 + n * 16;
      float* cp = C + (size_t)(crow0 + m * 16) * N_DIM + col;
      #pragma unroll
      for (int j = 0; j < 4; ++j)
        cp[(size_t)j * N_DIM] = acc[m][n][j];
    }
  }
}

// ---------------- K-split tail: cols 24576..24999, 64 tiles x 8 K-chunks ----------------

__device__ inline void mfma_tile_fb(const unsigned short* As, const unsigned short* Bs,
                                    f32x4 acc[4][4], int lane, int wr, int wc) {
  const int ar = lane & 15;
  const int ko = (lane >> 4) * 8;
  #pragma unroll
  for (int kk = 0; kk < 2; ++kk) {
    short8 a2[4], b2[4];
    #pragma unroll
    for (int m = 0; m < 4; ++m)
      a2[m] = *(const short8*)&As[(wr * 64 + m * 16 + ar) * 64 + kk * 32 + ko];
    #pragma unroll
    for (int n = 0; n < 4; ++n)
      b2[n] = *(const short8*)&Bs[(wc * 64 + n * 16 + ar) * 64 + kk * 32 + ko];
    #pragma unroll
    for (int m = 0; m < 4; ++m)
      #pragma unroll
      for (int n = 0; n < 4; ++n)
        acc[m][n] = __builtin_amdgcn_mfma_f32_16x16x32_bf16(a2[m], b2[n], acc[m][n], 0, 0, 0);
  }
}

__global__ __launch_bounds__(256, 2)
void gemm_rem_split_kernel(const unsigned short* __restrict__ A,
                           const unsigned short* __restrict__ Brem,  // rows 24576..25087
                           float* __restrict__ C) {
  __shared__ __align__(16) unsigned short As[128 * 64];
  __shared__ __align__(16) unsigned short Bs[128 * 64];
  const int bid = blockIdx.x;          // 512 blocks
  const int kc = bid & 7;              // K chunk 0..7
  const int tile = bid >> 3;           // 0..63
  const int tm = tile & 15;            // 16 M tiles of 128
  const int tnr = tile >> 4;           // 0..3 -> Brem rows tnr*128
  const int nsteps = (kc < 4) ? 63 : 62;
  const int kt0 = (kc < 4) ? kc * 63 : 252 + (kc - 4) * 62;
  const int tid = threadIdx.x;
  const int lane = tid & 63;
  const int w = tid >> 6;
  const int wr = w >> 1;
  const int wc = w & 1;
  f32x4 acc[4][4];
  const f32x4 z4 = {0.f, 0.f, 0.f, 0.f};
  #pragma unroll
  for (int i = 0; i < 4; ++i)
    #pragma unroll
    for (int j = 0; j < 4; ++j) acc[i][j] = z4;
  const int lrow = lane >> 3;
  const int lc16 = lane & 7;
  const unsigned short* ag = A + (size_t)(tm * 128 + w * 32 + lrow) * K_DIM + (size_t)kt0 * 64 + lc16 * 8;
  const unsigned short* bg = Brem + (size_t)(tnr * 128 + w * 32 + lrow) * K_DIM + (size_t)kt0 * 64 + lc16 * 8;
  for (int kt = 0; kt < nsteps; ++kt) {
    #pragma unroll
    for (int i = 0; i < 4; ++i) {
      GLDS16(ag + (size_t)(i * 8) * K_DIM, &As[(w * 32 + i * 8) * 64]);
      GLDS16(bg + (size_t)(i * 8) * K_DIM, &Bs[(w * 32 + i * 8) * 64]);
    }
    ag += 64; bg += 64;
    __syncthreads();
    mfma_tile_fb(As, Bs, acc, lane, wr, wc);
    __syncthreads();
  }
  const int crow0 = tm * 128 + wr * 64 + (lane >> 4) * 4;
  const int ccol0 = 24576 + tnr * 128 + wc * 64 + (lane & 15);
  #pragma unroll
  for (int m = 0; m < 4; ++m) {
    #pragma unroll
    for (int n = 0; n < 4; ++n) {
      const int col = ccol0 + n * 16;
      if (col < N_DIM) {
        float* cp = C + (size_t)(crow0 + m * 16) * N_DIM + col;
        #pragma unroll
        for (int j = 0; j < 4; ++j)
          unsafeAtomicAdd(cp + (size_t)j * N_DIM, acc[m][n][j]);
      }
    }
  }
}

// ---------------- fallback (r1-validated 128^2 reg-staged fp32 path) ----------------

__global__ __launch_bounds__(256, 2)
void gemm_fb_kernel(const float* __restrict__ A, const float* __restrict__ B,
                    float* __restrict__ C) {
  __shared__ __align__(16) unsigned short As[128 * 64];
  __shared__ __align__(16) unsigned short Bs[128 * 64];
  const int bid = blockIdx.x;
  const int wg = (bid & 7) * (3136 / 8) + (bid >> 3);
  const int tm = wg % 16;
  const int tn = wg / 16;
  const int tid = threadIdx.x;
  const int lane = tid & 63;
  const int w = tid >> 6;
  const int wr = w >> 1;
  const int wc = w & 1;
  f32x4 acc[4][4];
  const f32x4 z4 = {0.f, 0.f, 0.f, 0.f};
  #pragma unroll
  for (int i = 0; i < 4; ++i)
    #pragma unroll
    for (int j = 0; j < 4; ++j) acc[i][j] = z4;
  for (int kt = 0; kt < NT_K; ++kt) {
    const int k0 = kt * 64;
    #pragma unroll
    for (int r = 0; r < 4; ++r) {
      const int f0 = r * 512 + tid * 2;
      const int row = f0 >> 4;
      const int c4 = f0 & 15;
      const float* ga = A + (size_t)(tm * 128 + row) * K_DIM + k0 + c4 * 4;
      float4 v0 = *(const float4*)ga;
      float4 v1 = *(const float4*)(ga + 4);
      *(short8*)&As[row * 64 + c4 * 4] = pack8(v0, v1);
    }
    #pragma unroll
    for (int r = 0; r < 4; ++r) {
      const int f0 = r * 512 + tid * 2;
      const int row = f0 >> 4;
      const int c4 = f0 & 15;
      const int grow = tn * 128 + row;
      short8 s = {0, 0, 0, 0, 0, 0, 0, 0};
      if (grow < N_DIM) {
        const float* gb = B + (size_t)grow * K_DIM + k0 + c4 * 4;
        float4 v0 = *(const float4*)gb;
        float4 v1 = *(const float4*)(gb + 4);
        s = pack8(v0, v1);
      }
      *(short8*)&Bs[row * 64 + c4 * 4] = s;
    }
    __syncthreads();
    mfma_tile_fb(As, Bs, acc, lane, wr, wc);
    __syncthreads();
  }
  const int crow0 = tm * 128 + wr * 64 + (lane >> 4) * 4;
  const int ccol0 = tn * 128 + wc * 64 + (lane & 15);
  #pragma unroll
  for (int m = 0; m < 4; ++m) {
    #pragma unroll
    for (int n = 0; n < 4; ++n) {
      const int col = ccol0 + n * 16;
      if (col < N_DIM) {
        float* cp = C + (size_t)(crow0 + m * 16) * N_DIM + col;
        #pragma unroll
        for (int j = 0; j < 4; ++j)
          cp[(size_t)j * N_DIM] = acc[m][n][j];
      }
    }
  }
}

// ---------------- launch ----------------

extern "C" void kernel_launch(void* const* d_in, const int* in_sizes, int n_in,
                              void* d_out, int out_size, void* d_ws, size_t ws_size,
                              hipStream_t stream) {
  const float* A = (const float*)d_in[0];   // teacher_logits [2048][32000] fp32
  const float* B = (const float*)d_in[1];   // projection   [25000][32000] fp32
  float* C = (float*)d_out;                 // [2048][25000] fp32

  const size_t needA    = (size_t)M_DIM * K_DIM * 2;   // 131 MB
  const size_t needBrem = (size_t)512 * K_DIM * 2;     // 32.8 MB

  if (ws_size >= needA + needBrem) {
    unsigned short* wsA    = (unsigned short*)d_ws;
    unsigned short* wsBrem = wsA + (size_t)M_DIM * K_DIM;
    conv_a_kernel<<<2048, 256, 0, stream>>>(A, wsA);
    conv_b_rem_kernel<<<1024, 256, 0, stream>>>(B, wsBrem);
    zero_tail_kernel<<<512, 256, 0, stream>>>(C);
    (void)hipFuncSetAttribute((const void*)gemm8_kernel,
                              hipFuncAttributeMaxDynamicSharedMemorySize, 131072);
    gemm8_kernel<<<768, 512, 131072, stream>>>(wsA, B, C);            // cols 0..24575
    gemm_rem_split_kernel<<<512, 256, 0, stream>>>(wsA, wsBrem, C);   // cols 24576..24999
  } else {
    gemm_fb_kernel<<<3136, 256, 0, stream>>>(A, B, C);
  }
}

// Round 7
// 4697.798 us; speedup vs baseline: 1.1103x; 1.1001x over previous
//
#include <hip/hip_runtime.h>
#include <hip/hip_bf16.h>
#include <stdint.h>

#define M_DIM 2048
#define N_DIM 25000
#define K_DIM 32000
#define NT_K  500              // K_DIM / 64

typedef __attribute__((ext_vector_type(8))) short short8;
typedef __attribute__((ext_vector_type(4))) float f32x4;

typedef __attribute__((address_space(1))) const void* as1cv;
typedef __attribute__((address_space(3))) void* as3v;
#define GLDS16(g, l) __builtin_amdgcn_global_load_lds((as1cv)(g), (as3v)(l), 16, 0, 0)

// round-to-nearest-even fp32 -> bf16
__device__ inline unsigned short f2bf(float x) {
  union { float f; unsigned u; } c; c.f = x;
  unsigned u = c.u;
  return (unsigned short)((u + 0x7fffu + ((u >> 16) & 1u)) >> 16);
}

__device__ inline short8 pack8(float4 a, float4 b) {
  short8 s;
  s[0] = (short)f2bf(a.x); s[1] = (short)f2bf(a.y);
  s[2] = (short)f2bf(a.z); s[3] = (short)f2bf(a.w);
  s[4] = (short)f2bf(b.x); s[5] = (short)f2bf(b.y);
  s[6] = (short)f2bf(b.z); s[7] = (short)f2bf(b.w);
  return s;
}

// ---------------- convert kernels ----------------

__global__ __launch_bounds__(256) void conv_a_kernel(const float* __restrict__ in,
                                                     unsigned short* __restrict__ out) {
  const size_t n8 = (size_t)M_DIM * K_DIM / 8;
  const size_t stride = (size_t)gridDim.x * blockDim.x;
  for (size_t i = (size_t)blockIdx.x * blockDim.x + threadIdx.x; i < n8; i += stride) {
    const float4* p = (const float4*)(in + i * 8);
    float4 v0 = p[0], v1 = p[1];
    *(short8*)(out + i * 8) = pack8(v0, v1);
  }
}

// B rows 24576..25087 only (512 rows, zero-padded past 25000) for the rem kernel.
__global__ __launch_bounds__(256) void conv_b_rem_kernel(const float* __restrict__ in,
                                                         unsigned short* __restrict__ out) {
  const size_t n8 = 512 * (size_t)K_DIM / 8;
  const size_t stride = (size_t)gridDim.x * blockDim.x;
  const size_t k8 = K_DIM / 8;  // 4000
  for (size_t i = (size_t)blockIdx.x * blockDim.x + threadIdx.x; i < n8; i += stride) {
    const size_t row = i / k8;
    const size_t grow = 24576 + row;
    short8 s = {0, 0, 0, 0, 0, 0, 0, 0};
    if (grow < N_DIM) {
      const float4* p = (const float4*)(in + grow * K_DIM + (i % k8) * 8);
      float4 v0 = p[0], v1 = p[1];
      s = pack8(v0, v1);
    }
    *(short8*)(out + i * 8) = s;
  }
}

// zero the C tail strip (rows 0..2047, cols 24576..24999) for atomic accumulation
__global__ __launch_bounds__(256) void zero_tail_kernel(float* __restrict__ C) {
  const int ntail = 25000 - 24576;  // 424
  const size_t n = (size_t)M_DIM * ntail;
  const size_t stride = (size_t)gridDim.x * blockDim.x;
  for (size_t i = (size_t)blockIdx.x * blockDim.x + threadIdx.x; i < n; i += stride) {
    const size_t r = i / ntail, c = i % ntail;
    C[r * N_DIM + 24576 + c] = 0.f;
  }
}

// ------- 256x256 8-phase GEMM; A bf16 DMA, B fused fp32->bf16, quarter-unit pipeline -------
// r5/r6 failed on VGPR SPILL (acc=128 AGPR leaves 128 VGPR cap; they needed 148/180).
// This version: bf[2][2] (quadrant order Q00,Q10,Q11,Q01 + af-mh0 re-read) and ONE
// 16-row x 32-col B unit staged per phase (2 dwordx4 -> 8 f2bf -> 1 ds_write_b128,
// two alternating float4[2] sets) => ~90-110 VGPR, no spill.
//
// Unit map (tile n: buf0 units U0..U3 = (H0,k0),(H0,k1),(H1,k0),(H1,k1); buf1 U4..U7):
//   writes: P1:U5(t+1) P2:U6(t+1) P3:U7(t+1) P4:U0(t+2) P5:U1 P6:U2 P7:U3 P8:U4(t+3)
//   loads (2 phases ahead): P1:(t+1,H1,k1) P2:(t+2,H0,k0) P3:(t+2,H0,k1) P4:(t+2,H1,k0)
//                           P5:(t+2,H1,k1) P6:(t+3,H0,k0) P7:(t+3,H0,k1) P8:(t+3,H1,k0)
//   A DMA: P1: A(t+1) full (4), P5: A(t+2) full (4)  [after P4/P8 af-mh0 re-reads]
// FIFO ledger (invariant [LU5,LU6]=4 entering P1; order A-DMA -> VMC -> W -> L):
//   vmcnt: P1:6 P2:6 P3:2 P4:2 P5:6 P6:6 P7:2 P8:2 ; every wait drains 2-phase-old ops.

#define BARR  __builtin_amdgcn_s_barrier()
#define LGKM0 do { asm volatile("s_waitcnt lgkmcnt(0)" ::: "memory"); \
                   __builtin_amdgcn_sched_barrier(0); } while (0)
#define LGKM8 asm volatile("s_waitcnt lgkmcnt(8)" ::: "memory")
#define VMC6  asm volatile("s_waitcnt vmcnt(6)" ::: "memory")
#define VMC2  asm volatile("s_waitcnt vmcnt(2)" ::: "memory")
#define VMC0  asm volatile("s_waitcnt vmcnt(0)" ::: "memory")
#define PRIO1 __builtin_amdgcn_s_setprio(1)
#define PRIO0 __builtin_amdgcn_s_setprio(0)

#define READ_AF(P, MH) { _Pragma("unroll") for (int m2_ = 0; m2_ < 4; ++m2_) { \
  _Pragma("unroll") for (int kk_ = 0; kk_ < 2; ++kk_) \
    af[m2_][kk_] = *(const short8*)(rdA##P + (((MH) * 4 + m2_) * 2 + kk_) * 512); } }

// bf has no nh dimension anymore: overwritten per quadrant-pair
#define READ_BF(P, NH) { _Pragma("unroll") for (int n2_ = 0; n2_ < 2; ++n2_) { \
  _Pragma("unroll") for (int kk_ = 0; kk_ < 2; ++kk_) \
    bf[n2_][kk_] = *(const short8*)(rdB##P + (((NH) * 2 + n2_) * 2 + kk_) * 512); } }

#define MFMA_Q(MH, NH) { _Pragma("unroll") for (int kk_ = 0; kk_ < 2; ++kk_) { \
  _Pragma("unroll") for (int m2_ = 0; m2_ < 4; ++m2_) { \
  _Pragma("unroll") for (int n2_ = 0; n2_ < 2; ++n2_) \
    acc[(MH)*4+m2_][(NH)*2+n2_] = __builtin_amdgcn_mfma_f32_16x16x32_bf16( \
        af[m2_][kk_], bf[n2_][kk_], acc[(MH)*4+m2_][(NH)*2+n2_], 0, 0, 0); } } }

#define STAGE_A(P, KT, H) do { \
  const unsigned short* s_ = agp + (size_t)(H) * (128 * (size_t)K_DIM) + (size_t)(KT) * 64; \
  GLDS16(s_,      stA##P + (H) * 8192); \
  GLDS16(s_ + 32, stA##P + (H) * 8192 + 512); } while (0)

// one B unit = 16 rows x 32 cols: 2 dwordx4 per lane (pre-swizzled source chunk)
#define LOAD_BU(R, KT, H, KK) do { \
  const float* p_ = bq + (size_t)(H) * (128 * (size_t)K_DIM) + (size_t)(KT) * 64 + (KK) * 32; \
  (R)[0] = *(const float4*)(p_); (R)[1] = *(const float4*)(p_ + 4); } while (0)

// cvt + 1 ds_write_b128 reproducing the DMA's LDS image for that subtile
#define WRITE_BU(P, H, KK, R) \
  *(short8*)(stB##P + (H) * 8192 + (KK) * 512 + wboff) = pack8((R)[0], (R)[1])

__global__ __launch_bounds__(512, 2)
void gemm8_kernel(const unsigned short* __restrict__ A, const float* __restrict__ Bf,
                  float* __restrict__ C) {
  extern __shared__ __align__(16) unsigned short lds[];  // 131072 B
  unsigned short* const LA0 = lds;
  unsigned short* const LB0 = lds + 16384;
  unsigned short* const LA1 = lds + 32768;
  unsigned short* const LB1 = lds + 49152;

  const int bid = blockIdx.x;
  const int wg = (bid & 7) * 96 + (bid >> 3);   // bijective XCD chunking (768 % 8 == 0)
  const int tm = wg & 7;                        // M tile 0..7 (fastest: shares B panel)
  const int tn = wg >> 3;                       // N tile 0..95 (cols 0..24575)
  const int tid = threadIdx.x;
  const int lane = tid & 63;
  const int w = tid >> 6;        // wave 0..7
  const int wm = w >> 2;         // 2 waves in M (128 rows each)
  const int wn = w & 3;          // 4 waves in N (64 cols each)

  const int laneoff = (lane & 15) * 32 + (((lane >> 4) ^ ((lane >> 1) & 3)) << 3);
  const unsigned short* const rdA0 = LA0 + wm * (16 * 512) + laneoff;
  const unsigned short* const rdA1 = LA1 + wm * (16 * 512) + laneoff;
  const int bsub = (wn >> 1) * 16 + (wn & 1) * 8;
  const unsigned short* const rdB0 = LB0 + bsub * 512 + laneoff;
  const unsigned short* const rdB1 = LB1 + bsub * 512 + laneoff;

  const int srow = w * 16 + (lane >> 2);
  const int schunk = ((lane & 3) ^ ((lane >> 3) & 3)) * 8;   // swizzled source chunk
  const unsigned short* const agp = A + (size_t)(tm * 256 + srow) * K_DIM + schunk;
  const float* const bq = Bf + (size_t)(tn * 256 + srow) * K_DIM + schunk;
  unsigned short* const stA0 = LA0 + w * 1024;
  unsigned short* const stA1 = LA1 + w * 1024;
  unsigned short* const stB0 = LB0 + w * 1024;
  unsigned short* const stB1 = LB1 + w * 1024;
  const int wboff = (lane >> 2) * 32 + (lane & 3) * 8;  // ushort offset within one subtile

  f32x4 acc[8][4];
  const f32x4 z4 = {0.f, 0.f, 0.f, 0.f};
  #pragma unroll
  for (int i = 0; i < 8; ++i)
    #pragma unroll
    for (int j = 0; j < 4; ++j) acc[i][j] = z4;

  short8 af[4][2];      // current mh: 4 m-frags x 2 k-slices (32 VGPR)
  short8 bf[2][2];      // current nh only (16 VGPR)
  float4 lbO[2], lbE[2];  // two alternating B unit sets (16 VGPR)

  // ---- prologue: A(0) DMA; B(0) units + B(1).U4 serial; preload LU5,LU6 ----
  STAGE_A(0, 0, 0); STAGE_A(0, 0, 1);
  LOAD_BU(lbE, 0, 0, 0); VMC0; WRITE_BU(0, 0, 0, lbE);
  LOAD_BU(lbE, 0, 0, 1); VMC0; WRITE_BU(0, 0, 1, lbE);
  LOAD_BU(lbE, 0, 1, 0); VMC0; WRITE_BU(0, 1, 0, lbE);
  LOAD_BU(lbE, 0, 1, 1); VMC0; WRITE_BU(0, 1, 1, lbE);
  LOAD_BU(lbE, 1, 0, 0); VMC0; WRITE_BU(1, 0, 0, lbE);
  LOAD_BU(lbO, 1, 0, 1);   // LU5: W@P1
  LOAD_BU(lbE, 1, 1, 0);   // LU6: W@P2
  LGKM0; BARR;

  // ---- main loop: tiles (t, t+1), t = 0,2,...,496 ----
  #pragma unroll 1
  for (int it = 0; it < 249; ++it) {
    const int t = 2 * it;
    // P1: Q(0,0) tile t; A(t+1) full DMA; W U5(t+1); L (t+1,H1,k1)
    READ_AF(0, 0); READ_BF(0, 0);
    STAGE_A(1, t + 1, 0); STAGE_A(1, t + 1, 1);
    VMC6; WRITE_BU(1, 0, 1, lbO); LOAD_BU(lbO, t + 1, 1, 1);
    LGKM8; BARR; LGKM0; PRIO1; MFMA_Q(0, 0); PRIO0; BARR;
    // P2: Q(1,0); W U6(t+1); L (t+2,H0,k0)
    READ_AF(0, 1);
    VMC6; WRITE_BU(1, 1, 0, lbE); LOAD_BU(lbE, t + 2, 0, 0);
    BARR; LGKM0; PRIO1; MFMA_Q(1, 0); PRIO0; BARR;
    // P3: Q(1,1); W U7(t+1); L (t+2,H0,k1)
    READ_BF(0, 1);
    VMC2; WRITE_BU(1, 1, 1, lbO); LOAD_BU(lbO, t + 2, 0, 1);
    BARR; LGKM0; PRIO1; MFMA_Q(1, 1); PRIO0; BARR;
    // P4: Q(0,1) (af mh0 re-read); W U0(t+2); L (t+2,H1,k0)
    READ_AF(0, 0);
    VMC2; WRITE_BU(0, 0, 0, lbE); LOAD_BU(lbE, t + 2, 1, 0);
    BARR; LGKM0; PRIO1; MFMA_Q(0, 1); PRIO0; BARR;
    // P5: Q(0,0) tile t+1; A(t+2) full DMA; W U1(t+2); L (t+2,H1,k1)
    READ_AF(1, 0); READ_BF(1, 0);
    STAGE_A(0, t + 2, 0); STAGE_A(0, t + 2, 1);
    VMC6; WRITE_BU(0, 0, 1, lbO); LOAD_BU(lbO, t + 2, 1, 1);
    LGKM8; BARR; LGKM0; PRIO1; MFMA_Q(0, 0); PRIO0; BARR;
    // P6: Q(1,0); W U2(t+2); L (t+3,H0,k0)
    READ_AF(1, 1);
    VMC6; WRITE_BU(0, 1, 0, lbE); LOAD_BU(lbE, t + 3, 0, 0);
    BARR; LGKM0; PRIO1; MFMA_Q(1, 0); PRIO0; BARR;
    // P7: Q(1,1); W U3(t+2); L (t+3,H0,k1)
    READ_BF(1, 1);
    VMC2; WRITE_BU(0, 1, 1, lbO); LOAD_BU(lbO, t + 3, 0, 1);
    BARR; LGKM0; PRIO1; MFMA_Q(1, 1); PRIO0; BARR;
    // P8: Q(0,1); W U4(t+3); L (t+3,H1,k0)
    READ_AF(1, 0);
    VMC2; WRITE_BU(1, 0, 0, lbE); LOAD_BU(lbE, t + 3, 1, 0);
    BARR; LGKM0; PRIO1; MFMA_Q(0, 1); PRIO0; BARR;
  }

  // ---- tail: tile 498 (buf0; finish buf1.B(499) + A(499)), then tile 499 ----
  READ_AF(0, 0); READ_BF(0, 0);
  STAGE_A(1, 499, 0); STAGE_A(1, 499, 1);
  VMC6; WRITE_BU(1, 0, 1, lbO); LOAD_BU(lbO, 499, 1, 1);
  LGKM8; BARR; LGKM0; PRIO1; MFMA_Q(0, 0); PRIO0; BARR;
  READ_AF(0, 1);
  VMC6; WRITE_BU(1, 1, 0, lbE);
  BARR; LGKM0; PRIO1; MFMA_Q(1, 0); PRIO0; BARR;
  READ_BF(0, 1);
  VMC0; WRITE_BU(1, 1, 1, lbO);
  BARR; LGKM0; PRIO1; MFMA_Q(1, 1); PRIO0; BARR;
  READ_AF(0, 0);
  BARR; LGKM0; PRIO1; MFMA_Q(0, 1); PRIO0; BARR;
  READ_AF(1, 0); READ_BF(1, 0);
  LGKM8; BARR; LGKM0; PRIO1; MFMA_Q(0, 0); PRIO0; BARR;
  READ_AF(1, 1);
  BARR; LGKM0; PRIO1; MFMA_Q(1, 0); PRIO0; BARR;
  READ_BF(1, 1);
  BARR; LGKM0; PRIO1; MFMA_Q(1, 1); PRIO0; BARR;
  READ_AF(1, 0);
  LGKM0; PRIO1; MFMA_Q(0, 1); PRIO0;

  // ---- epilogue: C/D layout col=lane&15, row=(lane>>4)*4+j [m89-verified] ----
  const int crow0 = tm * 256 + wm * 128 + (lane >> 4) * 4;
  const int ccol0 = tn * 256 + wn * 64 + (lane & 15);
  #pragma unroll
  for (int m = 0; m < 8; ++m) {
    #pragma unroll
    for (int n = 0; n < 4; ++n) {
      const int col = ccol0 + n * 16;
      float* cp = C + (size_t)(crow0 + m * 16) * N_DIM + col;
      #pragma unroll
      for (int j = 0; j < 4; ++j)
        cp[(size_t)j * N_DIM] = acc[m][n][j];
    }
  }
}

// ---------------- K-split tail: cols 24576..24999, 64 tiles x 8 K-chunks ----------------

__device__ inline void mfma_tile_fb(const unsigned short* As, const unsigned short* Bs,
                                    f32x4 acc[4][4], int lane, int wr, int wc) {
  const int ar = lane & 15;
  const int ko = (lane >> 4) * 8;
  #pragma unroll
  for (int kk = 0; kk < 2; ++kk) {
    short8 a2[4], b2[4];
    #pragma unroll
    for (int m = 0; m < 4; ++m)
      a2[m] = *(const short8*)&As[(wr * 64 + m * 16 + ar) * 64 + kk * 32 + ko];
    #pragma unroll
    for (int n = 0; n < 4; ++n)
      b2[n] = *(const short8*)&Bs[(wc * 64 + n * 16 + ar) * 64 + kk * 32 + ko];
    #pragma unroll
    for (int m = 0; m < 4; ++m)
      #pragma unroll
      for (int n = 0; n < 4; ++n)
        acc[m][n] = __builtin_amdgcn_mfma_f32_16x16x32_bf16(a2[m], b2[n], acc[m][n], 0, 0, 0);
  }
}

__global__ __launch_bounds__(256, 2)
void gemm_rem_split_kernel(const unsigned short* __restrict__ A,
                           const unsigned short* __restrict__ Brem,  // rows 24576..25087
                           float* __restrict__ C) {
  __shared__ __align__(16) unsigned short As[128 * 64];
  __shared__ __align__(16) unsigned short Bs[128 * 64];
  const int bid = blockIdx.x;          // 512 blocks
  const int kc = bid & 7;
  const int tile = bid >> 3;
  const int tm = tile & 15;
  const int tnr = tile >> 4;
  const int nsteps = (kc < 4) ? 63 : 62;
  const int kt0 = (kc < 4) ? kc * 63 : 252 + (kc - 4) * 62;
  const int tid = threadIdx.x;
  const int lane = tid & 63;
  const int w = tid >> 6;
  const int wr = w >> 1;
  const int wc = w & 1;
  f32x4 acc[4][4];
  const f32x4 z4 = {0.f, 0.f, 0.f, 0.f};
  #pragma unroll
  for (int i = 0; i < 4; ++i)
    #pragma unroll
    for (int j = 0; j < 4; ++j) acc[i][j] = z4;
  const int lrow = lane >> 3;
  const int lc16 = lane & 7;
  const unsigned short* ag = A + (size_t)(tm * 128 + w * 32 + lrow) * K_DIM + (size_t)kt0 * 64 + lc16 * 8;
  const unsigned short* bg = Brem + (size_t)(tnr * 128 + w * 32 + lrow) * K_DIM + (size_t)kt0 * 64 + lc16 * 8;
  for (int kt = 0; kt < nsteps; ++kt) {
    #pragma unroll
    for (int i = 0; i < 4; ++i) {
      GLDS16(ag + (size_t)(i * 8) * K_DIM, &As[(w * 32 + i * 8) * 64]);
      GLDS16(bg + (size_t)(i * 8) * K_DIM, &Bs[(w * 32 + i * 8) * 64]);
    }
    ag += 64; bg += 64;
    __syncthreads();
    mfma_tile_fb(As, Bs, acc, lane, wr, wc);
    __syncthreads();
  }
  const int crow0 = tm * 128 + wr * 64 + (lane >> 4) * 4;
  const int ccol0 = 24576 + tnr * 128 + wc * 64 + (lane & 15);
  #pragma unroll
  for (int m = 0; m < 4; ++m) {
    #pragma unroll
    for (int n = 0; n < 4; ++n) {
      const int col = ccol0 + n * 16;
      if (col < N_DIM) {
        float* cp = C + (size_t)(crow0 + m * 16) * N_DIM + col;
        #pragma unroll
        for (int j = 0; j < 4; ++j)
          unsafeAtomicAdd(cp + (size_t)j * N_DIM, acc[m][n][j]);
      }
    }
  }
}

// ---------------- fallback (r1-validated 128^2 reg-staged fp32 path) ----------------

__global__ __launch_bounds__(256, 2)
void gemm_fb_kernel(const float* __restrict__ A, const float* __restrict__ B,
                    float* __restrict__ C) {
  __shared__ __align__(16) unsigned short As[128 * 64];
  __shared__ __align__(16) unsigned short Bs[128 * 64];
  const int bid = blockIdx.x;
  const int wg = (bid & 7) * (3136 / 8) + (bid >> 3);
  const int tm = wg % 16;
  const int tn = wg / 16;
  const int tid = threadIdx.x;
  const int lane = tid & 63;
  const int w = tid >> 6;
  const int wr = w >> 1;
  const int wc = w & 1;
  f32x4 acc[4][4];
  const f32x4 z4 = {0.f, 0.f, 0.f, 0.f};
  #pragma unroll
  for (int i = 0; i < 4; ++i)
    #pragma unroll
    for (int j = 0; j < 4; ++j) acc[i][j] = z4;
  for (int kt = 0; kt < NT_K; ++kt) {
    const int k0 = kt * 64;
    #pragma unroll
    for (int r = 0; r < 4; ++r) {
      const int f0 = r * 512 + tid * 2;
      const int row = f0 >> 4;
      const int c4 = f0 & 15;
      const float* ga = A + (size_t)(tm * 128 + row) * K_DIM + k0 + c4 * 4;
      float4 v0 = *(const float4*)ga;
      float4 v1 = *(const float4*)(ga + 4);
      *(short8*)&As[row * 64 + c4 * 4] = pack8(v0, v1);
    }
    #pragma unroll
    for (int r = 0; r < 4; ++r) {
      const int f0 = r * 512 + tid * 2;
      const int row = f0 >> 4;
      const int c4 = f0 & 15;
      const int grow = tn * 128 + row;
      short8 s = {0, 0, 0, 0, 0, 0, 0, 0};
      if (grow < N_DIM) {
        const float* gb = B + (size_t)grow * K_DIM + k0 + c4 * 4;
        float4 v0 = *(const float4*)gb;
        float4 v1 = *(const float4*)(gb + 4);
        s = pack8(v0, v1);
      }
      *(short8*)&Bs[row * 64 + c4 * 4] = s;
    }
    __syncthreads();
    mfma_tile_fb(As, Bs, acc, lane, wr, wc);
    __syncthreads();
  }
  const int crow0 = tm * 128 + wr * 64 + (lane >> 4) * 4;
  const int ccol0 = tn * 128 + wc * 64 + (lane & 15);
  #pragma unroll
  for (int m = 0; m < 4; ++m) {
    #pragma unroll
    for (int n = 0; n < 4; ++n) {
      const int col = ccol0 + n * 16;
      if (col < N_DIM) {
        float* cp = C + (size_t)(crow0 + m * 16) * N_DIM + col;
        #pragma unroll
        for (int j = 0; j < 4; ++j)
          cp[(size_t)j * N_DIM] = acc[m][n][j];
      }
    }
  }
}

// ---------------- launch ----------------

extern "C" void kernel_launch(void* const* d_in, const int* in_sizes, int n_in,
                              void* d_out, int out_size, void* d_ws, size_t ws_size,
                              hipStream_t stream) {
  const float* A = (const float*)d_in[0];   // teacher_logits [2048][32000] fp32
  const float* B = (const float*)d_in[1];   // projection   [25000][32000] fp32
  float* C = (float*)d_out;                 // [2048][25000] fp32

  const size_t needA    = (size_t)M_DIM * K_DIM * 2;   // 131 MB
  const size_t needBrem = (size_t)512 * K_DIM * 2;     // 32.8 MB

  if (ws_size >= needA + needBrem) {
    unsigned short* wsA    = (unsigned short*)d_ws;
    unsigned short* wsBrem = wsA + (size_t)M_DIM * K_DIM;
    conv_a_kernel<<<2048, 256, 0, stream>>>(A, wsA);
    conv_b_rem_kernel<<<1024, 256, 0, stream>>>(B, wsBrem);
    zero_tail_kernel<<<512, 256, 0, stream>>>(C);
    (void)hipFuncSetAttribute((const void*)gemm8_kernel,
                              hipFuncAttributeMaxDynamicSharedMemorySize, 131072);
    gemm8_kernel<<<768, 512, 131072, stream>>>(wsA, B, C);            // cols 0..24575
    gemm_rem_split_kernel<<<512, 256, 0, stream>>>(wsA, wsBrem, C);   // cols 24576..24999
  } else {
    gemm_fb_kernel<<<3136, 256, 0, stream>>>(A, B, C);
  }
}

// Round 8
// 3794.271 us; speedup vs baseline: 1.3747x; 1.2381x over previous
//
#include <hip/hip_runtime.h>
#include <hip/hip_bf16.h>
#include <stdint.h>

#define M_DIM 2048
#define N_DIM 25000
#define K_DIM 32000
#define N_PAD 25088            // 98 * 256
#define NT_K  500              // K_DIM / 64

typedef __attribute__((ext_vector_type(8))) short short8;
typedef __attribute__((ext_vector_type(4))) float f32x4;

typedef __attribute__((address_space(1))) const void* as1cv;
typedef __attribute__((address_space(3))) void* as3v;
#define GLDS16(g, l) __builtin_amdgcn_global_load_lds((as1cv)(g), (as3v)(l), 16, 0, 0)

// round-to-nearest-even fp32 -> bf16
__device__ inline unsigned short f2bf(float x) {
  union { float f; unsigned u; } c; c.f = x;
  unsigned u = c.u;
  return (unsigned short)((u + 0x7fffu + ((u >> 16) & 1u)) >> 16);
}

__device__ inline short8 pack8(float4 a, float4 b) {
  short8 s;
  s[0] = (short)f2bf(a.x); s[1] = (short)f2bf(a.y);
  s[2] = (short)f2bf(a.z); s[3] = (short)f2bf(a.w);
  s[4] = (short)f2bf(b.x); s[5] = (short)f2bf(b.y);
  s[6] = (short)f2bf(b.z); s[7] = (short)f2bf(b.w);
  return s;
}

// ---------------- convert kernels (fp32 -> bf16 in workspace) ----------------

__global__ __launch_bounds__(256) void conv_a_kernel(const float* __restrict__ in,
                                                     unsigned short* __restrict__ out) {
  const size_t n8 = (size_t)M_DIM * K_DIM / 8;
  const size_t stride = (size_t)gridDim.x * blockDim.x;
  for (size_t i = (size_t)blockIdx.x * blockDim.x + threadIdx.x; i < n8; i += stride) {
    const float4* p = (const float4*)(in + i * 8);
    float4 v0 = p[0], v1 = p[1];
    *(short8*)(out + i * 8) = pack8(v0, v1);
  }
}

// full B conversion for the main GEMM (rows 0..24999; pad rows zero-filled)
__global__ __launch_bounds__(256) void conv_b_kernel(const float* __restrict__ in,
                                                     unsigned short* __restrict__ out) {
  const size_t n8 = (size_t)N_PAD * K_DIM / 8;
  const size_t stride = (size_t)gridDim.x * blockDim.x;
  const size_t k8 = K_DIM / 8;  // 4000
  for (size_t i = (size_t)blockIdx.x * blockDim.x + threadIdx.x; i < n8; i += stride) {
    const size_t row = i / k8;
    short8 s = {0, 0, 0, 0, 0, 0, 0, 0};
    if (row < N_DIM) {
      const float4* p = (const float4*)(in + i * 8);
      float4 v0 = p[0], v1 = p[1];
      s = pack8(v0, v1);
    }
    *(short8*)(out + i * 8) = s;
  }
}

// zero the C tail strip (rows 0..2047, cols 24576..24999) for atomic accumulation
__global__ __launch_bounds__(256) void zero_tail_kernel(float* __restrict__ C) {
  const int ntail = 25000 - 24576;  // 424
  const size_t n = (size_t)M_DIM * ntail;
  const size_t stride = (size_t)gridDim.x * blockDim.x;
  for (size_t i = (size_t)blockIdx.x * blockDim.x + threadIdx.x; i < n; i += stride) {
    const size_t r = i / ntail, c = i % ntail;
    C[r * N_DIM + 24576 + c] = 0.f;
  }
}

// ---------------- 256x256 8-phase GEMM, deep prefetch (vmcnt(6)) ----------------
// r4 champion: A and B both bf16 (workspace), staged via global_load_lds width=16.
// LDS per buffer: A 256x64 bf16 as 32 subtiles (16 rows x 32 cols, 1024 B), then B.
// Swizzle within subtile: 16B-chunk c' = c ^ ((row>>1)&3), applied to the
// pre-swizzled GLOBAL source on stage and to the ds_read address (rule 21).
//
// Stage schedule (steady state, iteration = tiles t (buf0), t+1 (buf1)):
//   P1: A(t+1)h1 | P3: B(t+2)h0 | P4: B(t+2)h1 + A(t+2)h0 | P5: A(t+2)h1
//   P7: B(t+3)h0 | P8: B(t+3)h1 + A(t+3)h0
// vmcnt(6) at end-P4 / end-P8 only; every waited half has 3-5 phases of flight.

#define BARR  __builtin_amdgcn_s_barrier()
#define LGKM0 do { asm volatile("s_waitcnt lgkmcnt(0)" ::: "memory"); \
                   __builtin_amdgcn_sched_barrier(0); } while (0)
#define LGKM8 asm volatile("s_waitcnt lgkmcnt(8)" ::: "memory")
#define VMC6  asm volatile("s_waitcnt vmcnt(6)" ::: "memory")
#define VMC0  asm volatile("s_waitcnt vmcnt(0)" ::: "memory")
#define PRIO1 __builtin_amdgcn_s_setprio(1)
#define PRIO0 __builtin_amdgcn_s_setprio(0)

#define READ_AF(P, MH) { _Pragma("unroll") for (int m2_ = 0; m2_ < 4; ++m2_) { \
  _Pragma("unroll") for (int kk_ = 0; kk_ < 2; ++kk_) \
    af[m2_][kk_] = *(const short8*)(rdA##P + (((MH) * 4 + m2_) * 2 + kk_) * 512); } }

#define READ_BF(P, NH) { _Pragma("unroll") for (int n2_ = 0; n2_ < 2; ++n2_) { \
  _Pragma("unroll") for (int kk_ = 0; kk_ < 2; ++kk_) \
    bf[NH][n2_][kk_] = *(const short8*)(rdB##P + (((NH) * 2 + n2_) * 2 + kk_) * 512); } }

#define MFMA_Q(MH, NH) { _Pragma("unroll") for (int kk_ = 0; kk_ < 2; ++kk_) { \
  _Pragma("unroll") for (int m2_ = 0; m2_ < 4; ++m2_) { \
  _Pragma("unroll") for (int n2_ = 0; n2_ < 2; ++n2_) \
    acc[(MH)*4+m2_][(NH)*2+n2_] = __builtin_amdgcn_mfma_f32_16x16x32_bf16( \
        af[m2_][kk_], bf[NH][n2_][kk_], acc[(MH)*4+m2_][(NH)*2+n2_], 0, 0, 0); } } }

#define STAGE_A(P, KT, H) do { \
  const unsigned short* s_ = agp + (size_t)(H) * (128 * (size_t)K_DIM) + (size_t)(KT) * 64; \
  GLDS16(s_,      stA##P + (H) * 8192); \
  GLDS16(s_ + 32, stA##P + (H) * 8192 + 512); } while (0)

#define STAGE_B(P, KT, H) do { \
  const unsigned short* s_ = bgp + (size_t)(H) * (128 * (size_t)K_DIM) + (size_t)(KT) * 64; \
  GLDS16(s_,      stB##P + (H) * 8192); \
  GLDS16(s_ + 32, stB##P + (H) * 8192 + 512); } while (0)

__global__ __launch_bounds__(512, 2)
void gemm8_kernel(const unsigned short* __restrict__ A, const unsigned short* __restrict__ B,
                  float* __restrict__ C) {
  extern __shared__ __align__(16) unsigned short lds[];  // 131072 B
  unsigned short* const LA0 = lds;
  unsigned short* const LB0 = lds + 16384;
  unsigned short* const LA1 = lds + 32768;
  unsigned short* const LB1 = lds + 49152;

  const int bid = blockIdx.x;
  const int wg = (bid & 7) * 96 + (bid >> 3);   // bijective XCD chunking (768 % 8 == 0)
  const int tm = wg & 7;                        // M tile 0..7 (fastest: shares B panel)
  const int tn = wg >> 3;                       // N tile 0..95 (cols 0..24575)
  const int tid = threadIdx.x;
  const int lane = tid & 63;
  const int w = tid >> 6;        // wave 0..7
  const int wm = w >> 2;         // 2 waves in M (128 rows each)
  const int wn = w & 3;          // 4 waves in N (64 cols each)

  const int laneoff = (lane & 15) * 32 + (((lane >> 4) ^ ((lane >> 1) & 3)) << 3);
  const unsigned short* const rdA0 = LA0 + wm * (16 * 512) + laneoff;
  const unsigned short* const rdA1 = LA1 + wm * (16 * 512) + laneoff;
  const int bsub = (wn >> 1) * 16 + (wn & 1) * 8;
  const unsigned short* const rdB0 = LB0 + bsub * 512 + laneoff;
  const unsigned short* const rdB1 = LB1 + bsub * 512 + laneoff;

  const int srow = w * 16 + (lane >> 2);
  const int schunk = ((lane & 3) ^ ((lane >> 3) & 3)) * 8;
  const unsigned short* const agp = A + (size_t)(tm * 256 + srow) * K_DIM + schunk;
  const unsigned short* const bgp = B + (size_t)(tn * 256 + srow) * K_DIM + schunk;
  unsigned short* const stA0 = LA0 + w * 1024;
  unsigned short* const stA1 = LA1 + w * 1024;
  unsigned short* const stB0 = LB0 + w * 1024;
  unsigned short* const stB1 = LB1 + w * 1024;

  f32x4 acc[8][4];
  const f32x4 z4 = {0.f, 0.f, 0.f, 0.f};
  #pragma unroll
  for (int i = 0; i < 8; ++i)
    #pragma unroll
    for (int j = 0; j < 4; ++j) acc[i][j] = z4;

  short8 af[4][2];      // current mh: 4 m-frags x 2 k-slices
  short8 bf[2][2][2];   // [nh][n'][kk]

  // ---- prologue: tile0 (4 halves) + tile1 {Bh0, Bh1, Ah0}; drain tile0 ----
  STAGE_B(0, 0, 0); STAGE_B(0, 0, 1);
  STAGE_A(0, 0, 0); STAGE_A(0, 0, 1);
  STAGE_B(1, 1, 0); STAGE_B(1, 1, 1); STAGE_A(1, 1, 0);
  VMC6; BARR;

  // ---- main loop: tiles (t, t+1), t = 0,2,...,496 ----
  #pragma unroll 1
  for (int it = 0; it < 249; ++it) {
    const int t = 2 * it;
    // P1: reads for Q(0,0); stage A(t+1)h1 -> buf1
    READ_AF(0, 0); READ_BF(0, 0); STAGE_A(1, t + 1, 1);
    LGKM8; BARR; LGKM0; PRIO1; MFMA_Q(0, 0); PRIO0; BARR;
    // P2
    READ_BF(0, 1);
    BARR; LGKM0; PRIO1; MFMA_Q(0, 1); PRIO0; BARR;
    // P3: stage B(t+2)h0 -> buf0  [buf0.B free after P2]
    READ_AF(0, 1); STAGE_B(0, t + 2, 0);
    BARR; LGKM0; PRIO1; MFMA_Q(1, 1); PRIO0; BARR;
    // P4: stage B(t+2)h1 + A(t+2)h0 -> buf0  [buf0.A free after P3]; wait tile t+1
    STAGE_B(0, t + 2, 1); STAGE_A(0, t + 2, 0);
    BARR; PRIO1; MFMA_Q(1, 0); PRIO0; VMC6; BARR;
    // P5: stage A(t+2)h1 -> buf0
    READ_AF(1, 0); READ_BF(1, 0); STAGE_A(0, t + 2, 1);
    LGKM8; BARR; LGKM0; PRIO1; MFMA_Q(0, 0); PRIO0; BARR;
    // P6
    READ_BF(1, 1);
    BARR; LGKM0; PRIO1; MFMA_Q(0, 1); PRIO0; BARR;
    // P7: stage B(t+3)h0 -> buf1  [buf1.B free after P6]
    READ_AF(1, 1); STAGE_B(1, t + 3, 0);
    BARR; LGKM0; PRIO1; MFMA_Q(1, 1); PRIO0; BARR;
    // P8: stage B(t+3)h1 + A(t+3)h0 -> buf1  [buf1.A free after P7]; wait tile t+2
    STAGE_B(1, t + 3, 1); STAGE_A(1, t + 3, 0);
    BARR; PRIO1; MFMA_Q(1, 0); PRIO0; VMC6; BARR;
  }

  // ---- tail: tile 498 (buf0; stage A(499)h1), then tile 499 (buf1) ----
  READ_AF(0, 0); READ_BF(0, 0); STAGE_A(1, 499, 1);
  LGKM8; BARR; LGKM0; PRIO1; MFMA_Q(0, 0); PRIO0; BARR;
  READ_BF(0, 1);
  BARR; LGKM0; PRIO1; MFMA_Q(0, 1); PRIO0; BARR;
  READ_AF(0, 1);
  BARR; LGKM0; PRIO1; MFMA_Q(1, 1); PRIO0; BARR;
  BARR; PRIO1; MFMA_Q(1, 0); PRIO0; VMC0; BARR;
  READ_AF(1, 0); READ_BF(1, 0);
  LGKM8; BARR; LGKM0; PRIO1; MFMA_Q(0, 0); PRIO0; BARR;
  READ_BF(1, 1);
  BARR; LGKM0; PRIO1; MFMA_Q(0, 1); PRIO0; BARR;
  READ_AF(1, 1);
  BARR; LGKM0; PRIO1; MFMA_Q(1, 1); PRIO0; BARR;
  PRIO1; MFMA_Q(1, 0); PRIO0;

  // ---- epilogue: C/D layout col=lane&15, row=(lane>>4)*4+j [m89-verified] ----
  const int crow0 = tm * 256 + wm * 128 + (lane >> 4) * 4;
  const int ccol0 = tn * 256 + wn * 64 + (lane & 15);
  #pragma unroll
  for (int m = 0; m < 8; ++m) {
    #pragma unroll
    for (int n = 0; n < 4; ++n) {
      const int col = ccol0 + n * 16;
      float* cp = C + (size_t)(crow0 + m * 16) * N_DIM + col;
      #pragma unroll
      for (int j = 0; j < 4; ++j)
        cp[(size_t)j * N_DIM] = acc[m][n][j];
    }
  }
}

// ---------------- K-split tail: cols 24576..24999, 64 tiles x 8 K-chunks ----------------
// 512 blocks (2 co-resident/CU), each a 128^2 tile over 62-63 BK-steps; partials
// combined via native fp32 atomic add into the zeroed C tail strip.

__device__ inline void mfma_tile_fb(const unsigned short* As, const unsigned short* Bs,
                                    f32x4 acc[4][4], int lane, int wr, int wc) {
  const int ar = lane & 15;
  const int ko = (lane >> 4) * 8;
  #pragma unroll
  for (int kk = 0; kk < 2; ++kk) {
    short8 a2[4], b2[4];
    #pragma unroll
    for (int m = 0; m < 4; ++m)
      a2[m] = *(const short8*)&As[(wr * 64 + m * 16 + ar) * 64 + kk * 32 + ko];
    #pragma unroll
    for (int n = 0; n < 4; ++n)
      b2[n] = *(const short8*)&Bs[(wc * 64 + n * 16 + ar) * 64 + kk * 32 + ko];
    #pragma unroll
    for (int m = 0; m < 4; ++m)
      #pragma unroll
      for (int n = 0; n < 4; ++n)
        acc[m][n] = __builtin_amdgcn_mfma_f32_16x16x32_bf16(a2[m], b2[n], acc[m][n], 0, 0, 0);
  }
}

__global__ __launch_bounds__(256, 2)
void gemm_rem_split_kernel(const unsigned short* __restrict__ A,
                           const unsigned short* __restrict__ B,   // full bf16 ws (N_PAD rows)
                           float* __restrict__ C) {
  __shared__ __align__(16) unsigned short As[128 * 64];
  __shared__ __align__(16) unsigned short Bs[128 * 64];
  const int bid = blockIdx.x;          // 512 blocks
  const int kc = bid & 7;              // K chunk 0..7
  const int tile = bid >> 3;           // 0..63
  const int tm = tile & 15;            // 16 M tiles of 128
  const int tn = 192 + (tile >> 4);    // cols 24576..25087 (B ws zero-padded)
  const int nsteps = (kc < 4) ? 63 : 62;
  const int kt0 = (kc < 4) ? kc * 63 : 252 + (kc - 4) * 62;
  const int tid = threadIdx.x;
  const int lane = tid & 63;
  const int w = tid >> 6;
  const int wr = w >> 1;
  const int wc = w & 1;
  f32x4 acc[4][4];
  const f32x4 z4 = {0.f, 0.f, 0.f, 0.f};
  #pragma unroll
  for (int i = 0; i < 4; ++i)
    #pragma unroll
    for (int j = 0; j < 4; ++j) acc[i][j] = z4;
  const int lrow = lane >> 3;
  const int lc16 = lane & 7;
  const unsigned short* ag = A + (size_t)(tm * 128 + w * 32 + lrow) * K_DIM + (size_t)kt0 * 64 + lc16 * 8;
  const unsigned short* bg = B + (size_t)(tn * 128 + w * 32 + lrow) * K_DIM + (size_t)kt0 * 64 + lc16 * 8;
  for (int kt = 0; kt < nsteps; ++kt) {
    #pragma unroll
    for (int i = 0; i < 4; ++i) {
      GLDS16(ag + (size_t)(i * 8) * K_DIM, &As[(w * 32 + i * 8) * 64]);
      GLDS16(bg + (size_t)(i * 8) * K_DIM, &Bs[(w * 32 + i * 8) * 64]);
    }
    ag += 64; bg += 64;
    __syncthreads();
    mfma_tile_fb(As, Bs, acc, lane, wr, wc);
    __syncthreads();
  }
  const int crow0 = tm * 128 + wr * 64 + (lane >> 4) * 4;
  const int ccol0 = tn * 128 + wc * 64 + (lane & 15);
  #pragma unroll
  for (int m = 0; m < 4; ++m) {
    #pragma unroll
    for (int n = 0; n < 4; ++n) {
      const int col = ccol0 + n * 16;
      if (col < N_DIM) {
        float* cp = C + (size_t)(crow0 + m * 16) * N_DIM + col;
        #pragma unroll
        for (int j = 0; j < 4; ++j)
          unsafeAtomicAdd(cp + (size_t)j * N_DIM, acc[m][n][j]);
      }
    }
  }
}

// ---------------- fallback (r1-validated 128^2 reg-staged fp32 path) ----------------

__global__ __launch_bounds__(256, 2)
void gemm_fb_kernel(const float* __restrict__ A, const float* __restrict__ B,
                    float* __restrict__ C) {
  __shared__ __align__(16) unsigned short As[128 * 64];
  __shared__ __align__(16) unsigned short Bs[128 * 64];
  const int bid = blockIdx.x;
  const int wg = (bid & 7) * (3136 / 8) + (bid >> 3);
  const int tm = wg % 16;
  const int tn = wg / 16;
  const int tid = threadIdx.x;
  const int lane = tid & 63;
  const int w = tid >> 6;
  const int wr = w >> 1;
  const int wc = w & 1;
  f32x4 acc[4][4];
  const f32x4 z4 = {0.f, 0.f, 0.f, 0.f};
  #pragma unroll
  for (int i = 0; i < 4; ++i)
    #pragma unroll
    for (int j = 0; j < 4; ++j) acc[i][j] = z4;
  for (int kt = 0; kt < NT_K; ++kt) {
    const int k0 = kt * 64;
    #pragma unroll
    for (int r = 0; r < 4; ++r) {
      const int f0 = r * 512 + tid * 2;
      const int row = f0 >> 4;
      const int c4 = f0 & 15;
      const float* ga = A + (size_t)(tm * 128 + row) * K_DIM + k0 + c4 * 4;
      float4 v0 = *(const float4*)ga;
      float4 v1 = *(const float4*)(ga + 4);
      *(short8*)&As[row * 64 + c4 * 4] = pack8(v0, v1);
    }
    #pragma unroll
    for (int r = 0; r < 4; ++r) {
      const int f0 = r * 512 + tid * 2;
      const int row = f0 >> 4;
      const int c4 = f0 & 15;
      const int grow = tn * 128 + row;
      short8 s = {0, 0, 0, 0, 0, 0, 0, 0};
      if (grow < N_DIM) {
        const float* gb = B + (size_t)grow * K_DIM + k0 + c4 * 4;
        float4 v0 = *(const float4*)gb;
        float4 v1 = *(const float4*)(gb + 4);
        s = pack8(v0, v1);
      }
      *(short8*)&Bs[row * 64 + c4 * 4] = s;
    }
    __syncthreads();
    mfma_tile_fb(As, Bs, acc, lane, wr, wc);
    __syncthreads();
  }
  const int crow0 = tm * 128 + wr * 64 + (lane >> 4) * 4;
  const int ccol0 = tn * 128 + wc * 64 + (lane & 15);
  #pragma unroll
  for (int m = 0; m < 4; ++m) {
    #pragma unroll
    for (int n = 0; n < 4; ++n) {
      const int col = ccol0 + n * 16;
      if (col < N_DIM) {
        float* cp = C + (size_t)(crow0 + m * 16) * N_DIM + col;
        #pragma unroll
        for (int j = 0; j < 4; ++j)
          cp[(size_t)j * N_DIM] = acc[m][n][j];
      }
    }
  }
}

// ---------------- launch ----------------

extern "C" void kernel_launch(void* const* d_in, const int* in_sizes, int n_in,
                              void* d_out, int out_size, void* d_ws, size_t ws_size,
                              hipStream_t stream) {
  const float* A = (const float*)d_in[0];   // teacher_logits [2048][32000] fp32
  const float* B = (const float*)d_in[1];   // projection   [25000][32000] fp32
  float* C = (float*)d_out;                 // [2048][25000] fp32

  const size_t needA = (size_t)M_DIM * K_DIM * 2;   // 131 MB
  const size_t needB = (size_t)N_PAD * K_DIM * 2;   // 1.6 GB

  if (ws_size >= needA + needB) {
    unsigned short* wsA = (unsigned short*)d_ws;
    unsigned short* wsB = wsA + (size_t)M_DIM * K_DIM;
    conv_a_kernel<<<2048, 256, 0, stream>>>(A, wsA);
    conv_b_kernel<<<2048, 256, 0, stream>>>(B, wsB);
    zero_tail_kernel<<<512, 256, 0, stream>>>(C);
    (void)hipFuncSetAttribute((const void*)gemm8_kernel,
                              hipFuncAttributeMaxDynamicSharedMemorySize, 131072);
    gemm8_kernel<<<768, 512, 131072, stream>>>(wsA, wsB, C);          // cols 0..24575
    gemm_rem_split_kernel<<<512, 256, 0, stream>>>(wsA, wsB, C);      // cols 24576..24999
  } else {
    gemm_fb_kernel<<<3136, 256, 0, stream>>>(A, B, C);
  }
}

// Round 9
// 3785.807 us; speedup vs baseline: 1.3778x; 1.0022x over previous
//
#include <hip/hip_runtime.h>
#include <hip/hip_bf16.h>
#include <stdint.h>

#define M_DIM 2048
#define N_DIM 25000
#define K_DIM 32000
#define N_PAD 25088            // 98 * 256
#define NT_K  500              // K_DIM / 64

typedef __attribute__((ext_vector_type(8))) short short8;
typedef __attribute__((ext_vector_type(4))) float f32x4;

typedef __attribute__((address_space(1))) const void* as1cv;
typedef __attribute__((address_space(3))) void* as3v;
#define GLDS16(g, l) __builtin_amdgcn_global_load_lds((as1cv)(g), (as3v)(l), 16, 0, 0)

// round-to-nearest-even fp32 -> bf16
__device__ inline unsigned short f2bf(float x) {
  union { float f; unsigned u; } c; c.f = x;
  unsigned u = c.u;
  return (unsigned short)((u + 0x7fffu + ((u >> 16) & 1u)) >> 16);
}

__device__ inline short8 pack8(float4 a, float4 b) {
  short8 s;
  s[0] = (short)f2bf(a.x); s[1] = (short)f2bf(a.y);
  s[2] = (short)f2bf(a.z); s[3] = (short)f2bf(a.w);
  s[4] = (short)f2bf(b.x); s[5] = (short)f2bf(b.y);
  s[6] = (short)f2bf(b.z); s[7] = (short)f2bf(b.w);
  return s;
}

// ---------------- convert kernels (fp32 -> bf16 in workspace) ----------------

__global__ __launch_bounds__(256) void conv_a_kernel(const float* __restrict__ in,
                                                     unsigned short* __restrict__ out) {
  const size_t n8 = (size_t)M_DIM * K_DIM / 8;
  const size_t stride = (size_t)gridDim.x * blockDim.x;
  for (size_t i = (size_t)blockIdx.x * blockDim.x + threadIdx.x; i < n8; i += stride) {
    const float4* p = (const float4*)(in + i * 8);
    float4 v0 = p[0], v1 = p[1];
    *(short8*)(out + i * 8) = pack8(v0, v1);
  }
}

// full B conversion for the main GEMM (rows 0..24999; pad rows zero-filled)
__global__ __launch_bounds__(256) void conv_b_kernel(const float* __restrict__ in,
                                                     unsigned short* __restrict__ out) {
  const size_t n8 = (size_t)N_PAD * K_DIM / 8;
  const size_t stride = (size_t)gridDim.x * blockDim.x;
  const size_t k8 = K_DIM / 8;  // 4000
  for (size_t i = (size_t)blockIdx.x * blockDim.x + threadIdx.x; i < n8; i += stride) {
    const size_t row = i / k8;
    short8 s = {0, 0, 0, 0, 0, 0, 0, 0};
    if (row < N_DIM) {
      const float4* p = (const float4*)(in + i * 8);
      float4 v0 = p[0], v1 = p[1];
      s = pack8(v0, v1);
    }
    *(short8*)(out + i * 8) = s;
  }
}

// zero the C tail strip (rows 0..2047, cols 24576..24999) for atomic accumulation
__global__ __launch_bounds__(256) void zero_tail_kernel(float* __restrict__ C) {
  const int ntail = 25000 - 24576;  // 424
  const size_t n = (size_t)M_DIM * ntail;
  const size_t stride = (size_t)gridDim.x * blockDim.x;
  for (size_t i = (size_t)blockIdx.x * blockDim.x + threadIdx.x; i < n; i += stride) {
    const size_t r = i / ntail, c = i % ntail;
    C[r * N_DIM + 24576 + c] = 0.f;
  }
}

// ---------------- 256x256 8-phase GEMM, deep prefetch (vmcnt(6)) ----------------
// r8 champion MINUS the lgkmcnt(0)+sched_barrier(0) order-pins: reads are plain
// C++ LDS loads, so the compiler emits fine-grained counted lgkmcnt before each
// dependent MFMA (m97 behavior) and may overlap read latency with early MFMAs.
// Safety: all barriers retained; VMC6/VMC0 keep "memory" clobbers so reads of
// freshly-DMA'd regions (P1/P5) cannot hoist across the tile-boundary sync;
// within-tile LDS regions are stable since tile start, so read motion is safe;
// GLDS16 intrinsics may-alias LDS -> issue order (vmcnt ledger) preserved.
//
// Stage schedule (steady state, iteration = tiles t (buf0), t+1 (buf1)):
//   P1: A(t+1)h1 | P3: B(t+2)h0 | P4: B(t+2)h1 + A(t+2)h0 | P5: A(t+2)h1
//   P7: B(t+3)h0 | P8: B(t+3)h1 + A(t+3)h0
// vmcnt(6) at end-P4 / end-P8 only; every waited half has 3-5 phases of flight.

#define BARR  __builtin_amdgcn_s_barrier()
#define VMC6  asm volatile("s_waitcnt vmcnt(6)" ::: "memory")
#define VMC0  asm volatile("s_waitcnt vmcnt(0)" ::: "memory")
#define PRIO1 __builtin_amdgcn_s_setprio(1)
#define PRIO0 __builtin_amdgcn_s_setprio(0)

#define READ_AF(P, MH) { _Pragma("unroll") for (int m2_ = 0; m2_ < 4; ++m2_) { \
  _Pragma("unroll") for (int kk_ = 0; kk_ < 2; ++kk_) \
    af[m2_][kk_] = *(const short8*)(rdA##P + (((MH) * 4 + m2_) * 2 + kk_) * 512); } }

#define READ_BF(P, NH) { _Pragma("unroll") for (int n2_ = 0; n2_ < 2; ++n2_) { \
  _Pragma("unroll") for (int kk_ = 0; kk_ < 2; ++kk_) \
    bf[NH][n2_][kk_] = *(const short8*)(rdB##P + (((NH) * 2 + n2_) * 2 + kk_) * 512); } }

#define MFMA_Q(MH, NH) { _Pragma("unroll") for (int kk_ = 0; kk_ < 2; ++kk_) { \
  _Pragma("unroll") for (int m2_ = 0; m2_ < 4; ++m2_) { \
  _Pragma("unroll") for (int n2_ = 0; n2_ < 2; ++n2_) \
    acc[(MH)*4+m2_][(NH)*2+n2_] = __builtin_amdgcn_mfma_f32_16x16x32_bf16( \
        af[m2_][kk_], bf[NH][n2_][kk_], acc[(MH)*4+m2_][(NH)*2+n2_], 0, 0, 0); } } }

#define STAGE_A(P, KT, H) do { \
  const unsigned short* s_ = agp + (size_t)(H) * (128 * (size_t)K_DIM) + (size_t)(KT) * 64; \
  GLDS16(s_,      stA##P + (H) * 8192); \
  GLDS16(s_ + 32, stA##P + (H) * 8192 + 512); } while (0)

#define STAGE_B(P, KT, H) do { \
  const unsigned short* s_ = bgp + (size_t)(H) * (128 * (size_t)K_DIM) + (size_t)(KT) * 64; \
  GLDS16(s_,      stB##P + (H) * 8192); \
  GLDS16(s_ + 32, stB##P + (H) * 8192 + 512); } while (0)

__global__ __launch_bounds__(512, 2)
void gemm8_kernel(const unsigned short* __restrict__ A, const unsigned short* __restrict__ B,
                  float* __restrict__ C) {
  extern __shared__ __align__(16) unsigned short lds[];  // 131072 B
  unsigned short* const LA0 = lds;
  unsigned short* const LB0 = lds + 16384;
  unsigned short* const LA1 = lds + 32768;
  unsigned short* const LB1 = lds + 49152;

  const int bid = blockIdx.x;
  const int wg = (bid & 7) * 96 + (bid >> 3);   // bijective XCD chunking (768 % 8 == 0)
  const int tm = wg & 7;                        // M tile 0..7 (fastest: shares B panel)
  const int tn = wg >> 3;                       // N tile 0..95 (cols 0..24575)
  const int tid = threadIdx.x;
  const int lane = tid & 63;
  const int w = tid >> 6;        // wave 0..7
  const int wm = w >> 2;         // 2 waves in M (128 rows each)
  const int wn = w & 3;          // 4 waves in N (64 cols each)

  const int laneoff = (lane & 15) * 32 + (((lane >> 4) ^ ((lane >> 1) & 3)) << 3);
  const unsigned short* const rdA0 = LA0 + wm * (16 * 512) + laneoff;
  const unsigned short* const rdA1 = LA1 + wm * (16 * 512) + laneoff;
  const int bsub = (wn >> 1) * 16 + (wn & 1) * 8;
  const unsigned short* const rdB0 = LB0 + bsub * 512 + laneoff;
  const unsigned short* const rdB1 = LB1 + bsub * 512 + laneoff;

  const int srow = w * 16 + (lane >> 2);
  const int schunk = ((lane & 3) ^ ((lane >> 3) & 3)) * 8;
  const unsigned short* const agp = A + (size_t)(tm * 256 + srow) * K_DIM + schunk;
  const unsigned short* const bgp = B + (size_t)(tn * 256 + srow) * K_DIM + schunk;
  unsigned short* const stA0 = LA0 + w * 1024;
  unsigned short* const stA1 = LA1 + w * 1024;
  unsigned short* const stB0 = LB0 + w * 1024;
  unsigned short* const stB1 = LB1 + w * 1024;

  f32x4 acc[8][4];
  const f32x4 z4 = {0.f, 0.f, 0.f, 0.f};
  #pragma unroll
  for (int i = 0; i < 8; ++i)
    #pragma unroll
    for (int j = 0; j < 4; ++j) acc[i][j] = z4;

  short8 af[4][2];      // current mh: 4 m-frags x 2 k-slices
  short8 bf[2][2][2];   // [nh][n'][kk]

  // ---- prologue: tile0 (4 halves) + tile1 {Bh0, Bh1, Ah0}; drain tile0 ----
  STAGE_B(0, 0, 0); STAGE_B(0, 0, 1);
  STAGE_A(0, 0, 0); STAGE_A(0, 0, 1);
  STAGE_B(1, 1, 0); STAGE_B(1, 1, 1); STAGE_A(1, 1, 0);
  VMC6; BARR;

  // ---- main loop: tiles (t, t+1), t = 0,2,...,496 ----
  #pragma unroll 1
  for (int it = 0; it < 249; ++it) {
    const int t = 2 * it;
    // P1: reads for Q(0,0); stage A(t+1)h1 -> buf1
    READ_AF(0, 0); READ_BF(0, 0); STAGE_A(1, t + 1, 1);
    BARR; PRIO1; MFMA_Q(0, 0); PRIO0; BARR;
    // P2
    READ_BF(0, 1);
    BARR; PRIO1; MFMA_Q(0, 1); PRIO0; BARR;
    // P3: stage B(t+2)h0 -> buf0  [buf0.B free after P2]
    READ_AF(0, 1); STAGE_B(0, t + 2, 0);
    BARR; PRIO1; MFMA_Q(1, 1); PRIO0; BARR;
    // P4: stage B(t+2)h1 + A(t+2)h0 -> buf0  [buf0.A free after P3]; wait tile t+1
    STAGE_B(0, t + 2, 1); STAGE_A(0, t + 2, 0);
    BARR; PRIO1; MFMA_Q(1, 0); PRIO0; VMC6; BARR;
    // P5: stage A(t+2)h1 -> buf0
    READ_AF(1, 0); READ_BF(1, 0); STAGE_A(0, t + 2, 1);
    BARR; PRIO1; MFMA_Q(0, 0); PRIO0; BARR;
    // P6
    READ_BF(1, 1);
    BARR; PRIO1; MFMA_Q(0, 1); PRIO0; BARR;
    // P7: stage B(t+3)h0 -> buf1  [buf1.B free after P6]
    READ_AF(1, 1); STAGE_B(1, t + 3, 0);
    BARR; PRIO1; MFMA_Q(1, 1); PRIO0; BARR;
    // P8: stage B(t+3)h1 + A(t+3)h0 -> buf1  [buf1.A free after P7]; wait tile t+2
    STAGE_B(1, t + 3, 1); STAGE_A(1, t + 3, 0);
    BARR; PRIO1; MFMA_Q(1, 0); PRIO0; VMC6; BARR;
  }

  // ---- tail: tile 498 (buf0; stage A(499)h1), then tile 499 (buf1) ----
  READ_AF(0, 0); READ_BF(0, 0); STAGE_A(1, 499, 1);
  BARR; PRIO1; MFMA_Q(0, 0); PRIO0; BARR;
  READ_BF(0, 1);
  BARR; PRIO1; MFMA_Q(0, 1); PRIO0; BARR;
  READ_AF(0, 1);
  BARR; PRIO1; MFMA_Q(1, 1); PRIO0; BARR;
  BARR; PRIO1; MFMA_Q(1, 0); PRIO0; VMC0; BARR;
  READ_AF(1, 0); READ_BF(1, 0);
  BARR; PRIO1; MFMA_Q(0, 0); PRIO0; BARR;
  READ_BF(1, 1);
  BARR; PRIO1; MFMA_Q(0, 1); PRIO0; BARR;
  READ_AF(1, 1);
  BARR; PRIO1; MFMA_Q(1, 1); PRIO0; BARR;
  PRIO1; MFMA_Q(1, 0); PRIO0;

  // ---- epilogue: C/D layout col=lane&15, row=(lane>>4)*4+j [m89-verified] ----
  const int crow0 = tm * 256 + wm * 128 + (lane >> 4) * 4;
  const int ccol0 = tn * 256 + wn * 64 + (lane & 15);
  #pragma unroll
  for (int m = 0; m < 8; ++m) {
    #pragma unroll
    for (int n = 0; n < 4; ++n) {
      const int col = ccol0 + n * 16;
      float* cp = C + (size_t)(crow0 + m * 16) * N_DIM + col;
      #pragma unroll
      for (int j = 0; j < 4; ++j)
        cp[(size_t)j * N_DIM] = acc[m][n][j];
    }
  }
}

// ---------------- K-split tail: cols 24576..24999, 64 tiles x 8 K-chunks ----------------
// 512 blocks (2 co-resident/CU), each a 128^2 tile over 62-63 BK-steps; partials
// combined via native fp32 atomic add into the zeroed C tail strip.

__device__ inline void mfma_tile_fb(const unsigned short* As, const unsigned short* Bs,
                                    f32x4 acc[4][4], int lane, int wr, int wc) {
  const int ar = lane & 15;
  const int ko = (lane >> 4) * 8;
  #pragma unroll
  for (int kk = 0; kk < 2; ++kk) {
    short8 a2[4], b2[4];
    #pragma unroll
    for (int m = 0; m < 4; ++m)
      a2[m] = *(const short8*)&As[(wr * 64 + m * 16 + ar) * 64 + kk * 32 + ko];
    #pragma unroll
    for (int n = 0; n < 4; ++n)
      b2[n] = *(const short8*)&Bs[(wc * 64 + n * 16 + ar) * 64 + kk * 32 + ko];
    #pragma unroll
    for (int m = 0; m < 4; ++m)
      #pragma unroll
      for (int n = 0; n < 4; ++n)
        acc[m][n] = __builtin_amdgcn_mfma_f32_16x16x32_bf16(a2[m], b2[n], acc[m][n], 0, 0, 0);
  }
}

__global__ __launch_bounds__(256, 2)
void gemm_rem_split_kernel(const unsigned short* __restrict__ A,
                           const unsigned short* __restrict__ B,   // full bf16 ws (N_PAD rows)
                           float* __restrict__ C) {
  __shared__ __align__(16) unsigned short As[128 * 64];
  __shared__ __align__(16) unsigned short Bs[128 * 64];
  const int bid = blockIdx.x;          // 512 blocks
  const int kc = bid & 7;              // K chunk 0..7
  const int tile = bid >> 3;           // 0..63
  const int tm = tile & 15;            // 16 M tiles of 128
  const int tn = 192 + (tile >> 4);    // cols 24576..25087 (B ws zero-padded)
  const int nsteps = (kc < 4) ? 63 : 62;
  const int kt0 = (kc < 4) ? kc * 63 : 252 + (kc - 4) * 62;
  const int tid = threadIdx.x;
  const int lane = tid & 63;
  const int w = tid >> 6;
  const int wr = w >> 1;
  const int wc = w & 1;
  f32x4 acc[4][4];
  const f32x4 z4 = {0.f, 0.f, 0.f, 0.f};
  #pragma unroll
  for (int i = 0; i < 4; ++i)
    #pragma unroll
    for (int j = 0; j < 4; ++j) acc[i][j] = z4;
  const int lrow = lane >> 3;
  const int lc16 = lane & 7;
  const unsigned short* ag = A + (size_t)(tm * 128 + w * 32 + lrow) * K_DIM + (size_t)kt0 * 64 + lc16 * 8;
  const unsigned short* bg = B + (size_t)(tn * 128 + w * 32 + lrow) * K_DIM + (size_t)kt0 * 64 + lc16 * 8;
  for (int kt = 0; kt < nsteps; ++kt) {
    #pragma unroll
    for (int i = 0; i < 4; ++i) {
      GLDS16(ag + (size_t)(i * 8) * K_DIM, &As[(w * 32 + i * 8) * 64]);
      GLDS16(bg + (size_t)(i * 8) * K_DIM, &Bs[(w * 32 + i * 8) * 64]);
    }
    ag += 64; bg += 64;
    __syncthreads();
    mfma_tile_fb(As, Bs, acc, lane, wr, wc);
    __syncthreads();
  }
  const int crow0 = tm * 128 + wr * 64 + (lane >> 4) * 4;
  const int ccol0 = tn * 128 + wc * 64 + (lane & 15);
  #pragma unroll
  for (int m = 0; m < 4; ++m) {
    #pragma unroll
    for (int n = 0; n < 4; ++n) {
      const int col = ccol0 + n * 16;
      if (col < N_DIM) {
        float* cp = C + (size_t)(crow0 + m * 16) * N_DIM + col;
        #pragma unroll
        for (int j = 0; j < 4; ++j)
          unsafeAtomicAdd(cp + (size_t)j * N_DIM, acc[m][n][j]);
      }
    }
  }
}

// ---------------- fallback (r1-validated 128^2 reg-staged fp32 path) ----------------

__global__ __launch_bounds__(256, 2)
void gemm_fb_kernel(const float* __restrict__ A, const float* __restrict__ B,
                    float* __restrict__ C) {
  __shared__ __align__(16) unsigned short As[128 * 64];
  __shared__ __align__(16) unsigned short Bs[128 * 64];
  const int bid = blockIdx.x;
  const int wg = (bid & 7) * (3136 / 8) + (bid >> 3);
  const int tm = wg % 16;
  const int tn = wg / 16;
  const int tid = threadIdx.x;
  const int lane = tid & 63;
  const int w = tid >> 6;
  const int wr = w >> 1;
  const int wc = w & 1;
  f32x4 acc[4][4];
  const f32x4 z4 = {0.f, 0.f, 0.f, 0.f};
  #pragma unroll
  for (int i = 0; i < 4; ++i)
    #pragma unroll
    for (int j = 0; j < 4; ++j) acc[i][j] = z4;
  for (int kt = 0; kt < NT_K; ++kt) {
    const int k0 = kt * 64;
    #pragma unroll
    for (int r = 0; r < 4; ++r) {
      const int f0 = r * 512 + tid * 2;
      const int row = f0 >> 4;
      const int c4 = f0 & 15;
      const float* ga = A + (size_t)(tm * 128 + row) * K_DIM + k0 + c4 * 4;
      float4 v0 = *(const float4*)ga;
      float4 v1 = *(const float4*)(ga + 4);
      *(short8*)&As[row * 64 + c4 * 4] = pack8(v0, v1);
    }
    #pragma unroll
    for (int r = 0; r < 4; ++r) {
      const int f0 = r * 512 + tid * 2;
      const int row = f0 >> 4;
      const int c4 = f0 & 15;
      const int grow = tn * 128 + row;
      short8 s = {0, 0, 0, 0, 0, 0, 0, 0};
      if (grow < N_DIM) {
        const float* gb = B + (size_t)grow * K_DIM + k0 + c4 * 4;
        float4 v0 = *(const float4*)gb;
        float4 v1 = *(const float4*)(gb + 4);
        s = pack8(v0, v1);
      }
      *(short8*)&Bs[row * 64 + c4 * 4] = s;
    }
    __syncthreads();
    mfma_tile_fb(As, Bs, acc, lane, wr, wc);
    __syncthreads();
  }
  const int crow0 = tm * 128 + wr * 64 + (lane >> 4) * 4;
  const int ccol0 = tn * 128 + wc * 64 + (lane & 15);
  #pragma unroll
  for (int m = 0; m < 4; ++m) {
    #pragma unroll
    for (int n = 0; n < 4; ++n) {
      const int col = ccol0 + n * 16;
      if (col < N_DIM) {
        float* cp = C + (size_t)(crow0 + m * 16) * N_DIM + col;
        #pragma unroll
        for (int j = 0; j < 4; ++j)
          cp[(size_t)j * N_DIM] = acc[m][n][j];
      }
    }
  }
}

// ---------------- launch ----------------

extern "C" void kernel_launch(void* const* d_in, const int* in_sizes, int n_in,
                              void* d_out, int out_size, void* d_ws, size_t ws_size,
                              hipStream_t stream) {
  const float* A = (const float*)d_in[0];   // teacher_logits [2048][32000] fp32
  const float* B = (const float*)d_in[1];   // projection   [25000][32000] fp32
  float* C = (float*)d_out;                 // [2048][25000] fp32

  const size_t needA = (size_t)M_DIM * K_DIM * 2;   // 131 MB
  const size_t needB = (size_t)N_PAD * K_DIM * 2;   // 1.6 GB

  if (ws_size >= needA + needB) {
    unsigned short* wsA = (unsigned short*)d_ws;
    unsigned short* wsB = wsA + (size_t)M_DIM * K_DIM;
    conv_a_kernel<<<2048, 256, 0, stream>>>(A, wsA);
    conv_b_kernel<<<2048, 256, 0, stream>>>(B, wsB);
    zero_tail_kernel<<<512, 256, 0, stream>>>(C);
    (void)hipFuncSetAttribute((const void*)gemm8_kernel,
                              hipFuncAttributeMaxDynamicSharedMemorySize, 131072);
    gemm8_kernel<<<768, 512, 131072, stream>>>(wsA, wsB, C);          // cols 0..24575
    gemm_rem_split_kernel<<<512, 256, 0, stream>>>(wsA, wsB, C);      // cols 24576..24999
  } else {
    gemm_fb_kernel<<<3136, 256, 0, stream>>>(A, B, C);
  }
}